// Round 4
// baseline (194.410 us; speedup 1.0000x reference)
//
#include <hip/hip_runtime.h>
#include <math.h>

#define BATCH 8
#define T 1024
#define NH 8
#define NROW 8192
#define NEG_INF (-INFINITY)
#define SENT (-1.0e30f)
#define SC 0.180336880f      // 0.125 * log2(e)
#define LOG2E 1.442695041f

typedef __attribute__((ext_vector_type(8))) short short8;    // 8 bf16 (4 VGPRs)
typedef __attribute__((ext_vector_type(4))) float f32x4;
typedef __attribute__((ext_vector_type(16))) float f32x16;

// fp32 -> bf16 (RNE)
__device__ __forceinline__ ushort f2bf(float x) {
  uint u = __float_as_uint(x);
  return (ushort)((u + 0x7FFFu + ((u >> 16) & 1u)) >> 16);
}
__device__ __forceinline__ uint pack2(float a, float b) {
  return (uint)f2bf(a) | ((uint)f2bf(b) << 16);
}
// async global->LDS, 16B per lane; LDS dest = wave-uniform base + lane*16
__device__ __forceinline__ void gl_lds16(const ushort* g, ushort* l) {
  __builtin_amdgcn_global_load_lds(
      (const __attribute__((address_space(1))) unsigned int*)g,
      (__attribute__((address_space(3))) unsigned int*)l, 16, 0, 0);
}

// ---------------------------------------------------------------- merged prep
// blocks [0,1024): prep_fg (bf16 pack + gate log-softmax)
// blocks [1024,1536): prep_w (Wq/Wk -> bf16 concat)
// blocks [1536,1544): n_valid
__global__ __launch_bounds__(256) void k_prep(
    const float* __restrict__ feat, const float* __restrict__ pos,
    const int* __restrict__ tokens,
    const float* __restrict__ Wq, const float* __restrict__ Wk,
    const float* __restrict__ Wg, const float* __restrict__ bg,
    ushort* __restrict__ fbf, ushort* __restrict__ Wbf,
    float* __restrict__ gout, int* __restrict__ nvout) {
  const int bid = blockIdx.x;
  const int tid = threadIdx.x;

  if (bid < 1024) {
    // ---- prep_fg
    __shared__ __align__(16) float Ws[8192];  // 8 x 1024 fp32 = 32 KB
#pragma unroll
    for (int u = 0; u < 8; ++u)
      ((float4*)Ws)[u * 256 + tid] = ((const float4*)Wg)[u * 256 + tid];
    __syncthreads();

    const int w = tid >> 6, l = tid & 63;
    const int c0 = l * 16;
    const int row0 = bid * 8 + w * 2;

    float4 f[2][4];
#pragma unroll
    for (int r = 0; r < 2; ++r) {
      const int row = row0 + r;
      const float* src = (c0 < 512) ? (feat + (size_t)row * 512 + c0)
                                    : (pos + (size_t)row * 512 + (c0 - 512));
#pragma unroll
      for (int q4 = 0; q4 < 4; ++q4) f[r][q4] = *(const float4*)(src + q4 * 4);
      uint4 o0, o1;
      o0.x = pack2(f[r][0].x, f[r][0].y); o0.y = pack2(f[r][0].z, f[r][0].w);
      o0.z = pack2(f[r][1].x, f[r][1].y); o0.w = pack2(f[r][1].z, f[r][1].w);
      o1.x = pack2(f[r][2].x, f[r][2].y); o1.y = pack2(f[r][2].z, f[r][2].w);
      o1.z = pack2(f[r][3].x, f[r][3].y); o1.w = pack2(f[r][3].z, f[r][3].w);
      *(uint4*)(fbf + (size_t)row * 1024 + c0) = o0;
      *(uint4*)(fbf + (size_t)row * 1024 + c0 + 8) = o1;
    }

    float s[2][8];
#pragma unroll
    for (int h = 0; h < 8; ++h) {
      const float* wg = Ws + h * 1024 + c0;
      float4 w0 = *(const float4*)(wg + 0);
      float4 w1 = *(const float4*)(wg + 4);
      float4 w2 = *(const float4*)(wg + 8);
      float4 w3 = *(const float4*)(wg + 12);
#pragma unroll
      for (int r = 0; r < 2; ++r)
        s[r][h] = f[r][0].x * w0.x + f[r][0].y * w0.y + f[r][0].z * w0.z + f[r][0].w * w0.w
                + f[r][1].x * w1.x + f[r][1].y * w1.y + f[r][1].z * w1.z + f[r][1].w * w1.w
                + f[r][2].x * w2.x + f[r][2].y * w2.y + f[r][2].z * w2.z + f[r][2].w * w2.w
                + f[r][3].x * w3.x + f[r][3].y * w3.y + f[r][3].z * w3.z + f[r][3].w * w3.w;
    }
#pragma unroll
    for (int m = 1; m < 64; m <<= 1)
#pragma unroll
      for (int r = 0; r < 2; ++r)
#pragma unroll
        for (int h = 0; h < 8; ++h) s[r][h] += __shfl_xor(s[r][h], m, 64);
    if (l == 0) {
#pragma unroll
      for (int r = 0; r < 2; ++r) {
        float lg[8], mx = -1e30f;
#pragma unroll
        for (int h = 0; h < 8; ++h) { lg[h] = s[r][h] + bg[h]; mx = fmaxf(mx, lg[h]); }
        float sum = 0.f;
#pragma unroll
        for (int h = 0; h < 8; ++h) sum += __expf(lg[h] - mx);
        const float lse = mx + __logf(sum);
#pragma unroll
        for (int h = 0; h < 8; ++h) gout[(size_t)(row0 + r) * 8 + h] = lg[h] - lse;
      }
    }
  } else if (bid < 1536) {
    // ---- prep_w
    const int gid = (bid - 1024) * 256 + tid;  // 0..131071
    const int e0 = gid * 8;
    const int n = e0 >> 10, k = e0 & 1023;
    const float* src = (n < 512) ? (Wq + (size_t)n * 1024 + k)
                                 : (Wk + (size_t)(n - 512) * 1024 + k);
    float4 a = *(const float4*)src;
    float4 b = *(const float4*)(src + 4);
    uint4 o;
    o.x = pack2(a.x, a.y); o.y = pack2(a.z, a.w);
    o.z = pack2(b.x, b.y); o.w = pack2(b.z, b.w);
    *(uint4*)(Wbf + (size_t)n * 1024 + k) = o;
  } else {
    // ---- n_valid
    const int b = bid - 1536;
    int cnt = 0;
    for (int i = tid; i < T; i += 256) cnt += (tokens[b * T + i] != 0) ? 1 : 0;
    __shared__ int s[256];
    s[tid] = cnt;
    __syncthreads();
    for (int st = 128; st > 0; st >>= 1) {
      if (tid < st) s[tid] += s[tid + st];
      __syncthreads();
    }
    if (tid == 0) nvout[b] = s[0];
  }
}

// ---------------------------------------------------------------- fused q/k GEMM
// 128x128 tile, BK=64, 2-phase prefetch double-buffer (stage next BEFORE compute),
// one barrier per k-step; swapped-operand MFMA -> ushort4 stores; XCD-chunked swizzle.
__global__ __launch_bounds__(256) void k_gemm(
    const ushort* __restrict__ fbf, const ushort* __restrict__ Wbf,
    const float* __restrict__ bq, const float* __restrict__ bk,
    ushort* __restrict__ qbuf, ushort* __restrict__ kbuf) {
  const int g = blockIdx.x + 8 * blockIdx.y;   // dispatch-linear id; xcd ~ g%8
  const int wid = (g & 7) * 64 + (g >> 3);     // bijective (512 = 8*64)
  const int n0 = (wid & 7) * 128;
  const int m0 = (wid >> 3) * 128;
  const int tid = threadIdx.x;
  const int w = tid >> 6, l = tid & 63;
  const int lo = l & 15, quad = l >> 4;
  const int wm0 = (w >> 1) * 64, wn0 = (w & 1) * 64;

  __shared__ ushort As[2][128 * 64];  // 2 x 16 KB, linear row-major [128][64]
  __shared__ ushort Bs[2][128 * 64];

  f32x4 acc[4][4];
#pragma unroll
  for (int i = 0; i < 4; ++i)
#pragma unroll
    for (int j = 0; j < 4; ++j) acc[i][j] = (f32x4){0.f, 0.f, 0.f, 0.f};

  const int c8 = (tid & 7) * 8;
  const int r0 = tid >> 3;

  auto stage = [&](int buf, int k0) {
#pragma unroll
    for (int u = 0; u < 4; ++u) {
      gl_lds16(fbf + (size_t)(m0 + u * 32 + r0) * 1024 + k0 + c8,
               As[buf] + (size_t)w * 512 + u * 2048);
      gl_lds16(Wbf + (size_t)(n0 + u * 32 + r0) * 1024 + k0 + c8,
               Bs[buf] + (size_t)w * 512 + u * 2048);
    }
  };

  stage(0, 0);
  int cur = 0;
  for (int k0 = 0; k0 < 1024; k0 += 64) {
    __syncthreads();  // drains vmcnt: buf[cur] staged; buf[cur^1] readers done
    if (k0 + 64 < 1024) stage(cur ^ 1, k0 + 64);  // in flight during compute
    const ushort* pA = As[cur];
    const ushort* pB = Bs[cur];
#pragma unroll
    for (int kk = 0; kk < 2; ++kk) {
      short8 af[4], bfr[4];
#pragma unroll
      for (int mi = 0; mi < 4; ++mi)
        af[mi] = *(const short8*)(pA + (size_t)(wm0 + mi * 16 + lo) * 64 + kk * 32 + quad * 8);
#pragma unroll
      for (int ni = 0; ni < 4; ++ni)
        bfr[ni] = *(const short8*)(pB + (size_t)(wn0 + ni * 16 + lo) * 64 + kk * 32 + quad * 8);
#pragma unroll
      for (int mi = 0; mi < 4; ++mi)
#pragma unroll
        for (int ni = 0; ni < 4; ++ni)  // swapped: rows=n, cols=m
          acc[mi][ni] = __builtin_amdgcn_mfma_f32_16x16x32_bf16(bfr[ni], af[mi], acc[mi][ni], 0, 0, 0);
    }
    cur ^= 1;
  }

  // epilogue: lane owns row m, 4 consecutive n per (ni)
  float4 bias4[4];
#pragma unroll
  for (int ni = 0; ni < 4; ++ni) {
    const int gn = n0 + wn0 + ni * 16 + quad * 4;
    bias4[ni] = *(const float4*)((gn < 512) ? (bq + gn) : (bk + gn - 512));
  }
#pragma unroll
  for (int mi = 0; mi < 4; ++mi) {
    const int m = m0 + wm0 + mi * 16 + lo;
#pragma unroll
    for (int ni = 0; ni < 4; ++ni) {
      const int gn = n0 + wn0 + ni * 16 + quad * 4;
      ushort* dst = (gn < 512) ? (qbuf + (size_t)m * 512 + gn)
                               : (kbuf + (size_t)m * 512 + gn - 512);
      ushort4 o;
      o.x = f2bf(acc[mi][ni][0] + bias4[ni].x);
      o.y = f2bf(acc[mi][ni][1] + bias4[ni].y);
      o.z = f2bf(acc[mi][ni][2] + bias4[ni].z);
      o.w = f2bf(acc[mi][ni][3] + bias4[ni].w);
      *(ushort4*)dst = o;
    }
  }
}

// ---------------------------------------------------------------- pass1 (unchanged)
// K dbuf LDS, swapped 16x16 MFMA, maskless interior tiles.
__global__ __launch_bounds__(256) void k_pass1(
    const ushort* __restrict__ q, const ushort* __restrict__ kv,
    const float* __restrict__ g, const int* __restrict__ nvp,
    float* __restrict__ Wt) {
  const int it = blockIdx.x, h = blockIdx.y, b = blockIdx.z;
  const int nv = nvp[b];
  const int i0 = it * 64;
  const int tid = threadIdx.x;
  const int w = tid >> 6, l = tid & 63;
  const int lo = l & 15, quad = l >> 4;

  __shared__ ushort Ks[2][64 * 64];  // 2 x 8 KB

  const int i = i0 + w * 16 + lo;
  const ushort* qp = q + (size_t)(b * T + i) * 512 + h * 64 + quad * 8;
  const short8 a0 = *(const short8*)qp;
  const short8 a1 = *(const short8*)(qp + 32);

  float lsum = 0.f;
  const int ntile = ((nv + 63) >> 6) - it;

  if (ntile > 0) {
    auto stage = [&](int buf, int jt) {
#pragma unroll
      for (int u = 0; u < 2; ++u) {
        const int s = u * 256 + tid;
        const int row = s >> 3, c = s & 7;
        gl_lds16(kv + (size_t)(b * T + jt * 64 + row) * 512 + h * 64 + ((c ^ (row & 7)) * 8),
                 Ks[buf] + (size_t)(u * 256 + w * 64) * 8);
      }
    };
    stage(0, it);
    __syncthreads();
    for (int s = 0; s < ntile; ++s) {
      if (s + 1 < ntile) stage((s + 1) & 1, it + s + 1);
      const ushort* kbase = Ks[s & 1];
      const int j0 = (it + s) * 64;
      const bool diag = (s == 0);
      const bool masked = diag | (j0 + 64 > nv);
#pragma unroll
      for (int ni = 0; ni < 4; ++ni) {
        if (diag && ni < w) continue;  // sub-tile fully below diagonal (wave-uniform)
        const int rw = ni * 16 + lo;
        const short8 b0 = *(const short8*)(kbase + (size_t)rw * 64 + ((quad ^ (rw & 7)) * 8));
        const short8 b1 = *(const short8*)(kbase + (size_t)rw * 64 + (((4 + quad) ^ (rw & 7)) * 8));
        f32x4 acc = (f32x4){0.f, 0.f, 0.f, 0.f};
        acc = __builtin_amdgcn_mfma_f32_16x16x32_bf16(b0, a0, acc, 0, 0, 0);
        acc = __builtin_amdgcn_mfma_f32_16x16x32_bf16(b1, a1, acc, 0, 0, 0);
        if (!masked) {
#pragma unroll
          for (int r = 0; r < 4; ++r) lsum += __builtin_amdgcn_exp2f(acc[r] * SC);
        } else {
          const int jb = j0 + ni * 16 + quad * 4;
#pragma unroll
          for (int r = 0; r < 4; ++r) {
            const int j = jb + r;
            if (j > i && j < nv) lsum += __builtin_amdgcn_exp2f(acc[r] * SC);
          }
        }
      }
      __syncthreads();
    }
  }

  lsum += __shfl_xor(lsum, 16, 64);
  lsum += __shfl_xor(lsum, 32, 64);
  if (quad == 0) {
    const size_t row = (size_t)(b * T) + i;
    Wt[(size_t)h * NROW + row] =
        (lsum > 0.f) ? (g[row * 8 + h] - __logf(lsum)) : NEG_INF;
  }
}

// ---------------------------------------------------------------- pass2: 32x32x16 MFMA
// Wave = 32i x 32j x 8h. K-frag: 1 ds_read_b128/MFMA (halved LDS traffic);
// Q + weights fully in registers. K tile 64 KB LDS, chunk swizzle c^(row&15).
__global__ __launch_bounds__(256) void k_pass2(
    const ushort* __restrict__ q, const ushort* __restrict__ kv,
    const float* __restrict__ Wt, const int* __restrict__ nvp,
    float* __restrict__ out) {
  const int jt = blockIdx.x, it = blockIdx.y, b = blockIdx.z;
  const int nv = nvp[b];
  const int i0 = it * 64, j0 = jt * 64;
  const int tid = threadIdx.x;

  if (jt < it || j0 >= nv) {
    const int r0 = tid >> 4, c0 = (tid & 15) * 4;
    float4 v; v.x = v.y = v.z = v.w = SENT;
#pragma unroll
    for (int u = 0; u < 4; ++u)
      *(float4*)(out + ((size_t)(b * T + i0 + r0 + u * 16)) * T + j0 + c0) = v;
    return;
  }

  const int w = tid >> 6, l = tid & 63;
  const int lc = l & 31, hi = l >> 5;
  const int ih = (w & 1) * 32, jh = (w >> 1) * 32;
  const int i = i0 + ih + lc;

  __shared__ ushort Ks[64 * 512];  // 64 KB; row-linear, 16B-chunk c ^= (row&15)

  // stage: wave w stages rows w,4+w,...,60+w; one gl_lds per row (64 lanes x 16B)
#pragma unroll
  for (int u = 0; u < 16; ++u) {
    const int row = u * 4 + w;
    gl_lds16(kv + (size_t)(b * T + j0 + row) * 512 + ((l ^ (row & 15)) * 8),
             Ks + (size_t)row * 512);
  }

  // Q fragments (B-operand: col=i=lc, k-half=hi) + per-row weights; overlap staging
  const ushort* qb = q + (size_t)(b * T + i) * 512;
  short8 qf[8][4];
  float wl[8];
#pragma unroll
  for (int h = 0; h < 8; ++h) {
#pragma unroll
    for (int kh = 0; kh < 4; ++kh)
      qf[h][kh] = *(const short8*)(qb + h * 64 + kh * 16 + hi * 8);
    wl[h] = Wt[(size_t)h * NROW + b * T + i] * LOG2E;  // -inf stays -inf
  }

  float se[16];
#pragma unroll
  for (int r = 0; r < 16; ++r) se[r] = 0.f;

  __syncthreads();  // staging complete

  if (jt == it && jh + 32 <= ih) {  // wave fully below diagonal (w==1 on diag tile)
    const size_t orow = ((size_t)(b * T + i)) * T;
    float4 v; v.x = v.y = v.z = v.w = SENT;
#pragma unroll
    for (int g2 = 0; g2 < 4; ++g2)
      *(float4*)(out + orow + j0 + jh + g2 * 8 + hi * 4) = v;
    return;
  }

  // A-frag: row = jh+lc (j), k-half = hi
  const ushort* krow = Ks + (size_t)(jh + lc) * 512;
  const int sw = lc & 15;  // (jh+lc)&15 == lc&15 since jh%32==0
#pragma unroll
  for (int h = 0; h < 8; ++h) {
    f32x16 acc;
#pragma unroll
    for (int r = 0; r < 16; ++r) acc[r] = 0.f;
#pragma unroll
    for (int kh = 0; kh < 4; ++kh) {
      const short8 af = *(const short8*)(krow + ((size_t)((h * 8 + kh * 2 + hi) ^ sw) * 8));
      acc = __builtin_amdgcn_mfma_f32_32x32x16_bf16(af, qf[h][kh], acc, 0, 0, 0);
    }
#pragma unroll
    for (int r = 0; r < 16; ++r)
      se[r] += __builtin_amdgcn_exp2f(acc[r] * SC + wl[h]);
  }

  // C layout: col(i)=lc, row(j) = (reg&3) + 8*(reg>>2) + 4*hi
  const size_t orow = ((size_t)(b * T + i)) * T;
  const bool maskfree = (j0 + jh > i0 + ih + 31) && (j0 + jh + 32 <= nv);
  if (maskfree) {
#pragma unroll
    for (int g2 = 0; g2 < 4; ++g2) {
      float4 v;
      v.x = fmaxf(__logf(se[g2 * 4 + 0]), SENT);
      v.y = fmaxf(__logf(se[g2 * 4 + 1]), SENT);
      v.z = fmaxf(__logf(se[g2 * 4 + 2]), SENT);
      v.w = fmaxf(__logf(se[g2 * 4 + 3]), SENT);
      *(float4*)(out + orow + j0 + jh + g2 * 8 + hi * 4) = v;
    }
  } else {
#pragma unroll
    for (int g2 = 0; g2 < 4; ++g2) {
      const int jb = j0 + jh + g2 * 8 + hi * 4;
      float4 v;
      v.x = (jb + 0 > i && jb + 0 < nv) ? fmaxf(__logf(se[g2 * 4 + 0]), SENT) : SENT;
      v.y = (jb + 1 > i && jb + 1 < nv) ? fmaxf(__logf(se[g2 * 4 + 1]), SENT) : SENT;
      v.z = (jb + 2 > i && jb + 2 < nv) ? fmaxf(__logf(se[g2 * 4 + 2]), SENT) : SENT;
      v.w = (jb + 3 > i && jb + 3 < nv) ? fmaxf(__logf(se[g2 * 4 + 3]), SENT) : SENT;
      *(float4*)(out + orow + jb) = v;
    }
  }
}

// ---------------------------------------------------------------- launch
extern "C" void kernel_launch(void* const* d_in, const int* in_sizes, int n_in,
                              void* d_out, int out_size, void* d_ws, size_t ws_size,
                              hipStream_t stream) {
  (void)in_sizes; (void)n_in; (void)out_size; (void)ws_size;
  const float* feat = (const float*)d_in[0];
  const float* pos  = (const float*)d_in[1];
  const int* tokens = (const int*)d_in[2];
  const float* Wq = (const float*)d_in[3];
  const float* bq = (const float*)d_in[4];
  const float* Wk = (const float*)d_in[5];
  const float* bk = (const float*)d_in[6];
  const float* Wg = (const float*)d_in[7];
  const float* bg = (const float*)d_in[8];
  float* out = (float*)d_out;

  // workspace: qbuf 8.4M | kbuf 8.4M | Wbf 2M | gbuf 256K | Wt 256K | nv
  ushort* qbuf = (ushort*)d_ws;
  ushort* kbuf = qbuf + (size_t)NROW * 512;
  ushort* Wbf  = kbuf + (size_t)NROW * 512;
  float*  gbuf = (float*)(Wbf + (size_t)1024 * 1024);
  float*  Wt   = gbuf + (size_t)NROW * NH;
  int*    nv   = (int*)(Wt + (size_t)NH * NROW);

  // fbf (bf16 concat of feat,pos) lives in d_out; consumed by k_gemm,
  // fully overwritten later by k_pass2.
  ushort* fbf = (ushort*)d_out;

  k_prep<<<dim3(1544), dim3(256), 0, stream>>>(feat, pos, tokens, Wq, Wk, Wg, bg,
                                               fbf, Wbf, gbuf, nv);
  k_gemm<<<dim3(8, 64), dim3(256), 0, stream>>>(fbf, Wbf, bq, bk, qbuf, kbuf);
  k_pass1<<<dim3(16, NH, BATCH), dim3(256), 0, stream>>>(qbuf, kbuf, gbuf, nv, Wt);
  k_pass2<<<dim3(16, 16, BATCH), dim3(256), 0, stream>>>(qbuf, kbuf, Wt, nv, out);
}

// Round 5
// 182.453 us; speedup vs baseline: 1.0655x; 1.0655x over previous
//
#include <hip/hip_runtime.h>
#include <math.h>

#define BATCH 8
#define T 1024
#define NH 8
#define NROW 8192
#define NEG_INF (-INFINITY)
#define SENT (-1.0e30f)
#define SC 0.180336880f      // 0.125 * log2(e)
#define LOG2E 1.442695041f

typedef __attribute__((ext_vector_type(8))) short short8;    // 8 bf16 (4 VGPRs)
typedef __attribute__((ext_vector_type(4))) float f32x4;

// fp32 -> bf16 (RNE)
__device__ __forceinline__ ushort f2bf(float x) {
  uint u = __float_as_uint(x);
  return (ushort)((u + 0x7FFFu + ((u >> 16) & 1u)) >> 16);
}
__device__ __forceinline__ uint pack2(float a, float b) {
  return (uint)f2bf(a) | ((uint)f2bf(b) << 16);
}
// async global->LDS, 16B per lane; LDS dest = wave-uniform base + lane*16
__device__ __forceinline__ void gl_lds16(const ushort* g, ushort* l) {
  __builtin_amdgcn_global_load_lds(
      (const __attribute__((address_space(1))) unsigned int*)g,
      (__attribute__((address_space(3))) unsigned int*)l, 16, 0, 0);
}

// ---------------------------------------------------------------- merged prep
// blocks [0,1024): prep_fg (bf16 pack + gate log-softmax)
// blocks [1024,1536): prep_w (Wq/Wk -> bf16 concat)
// blocks [1536,1544): n_valid
__global__ __launch_bounds__(256) void k_prep(
    const float* __restrict__ feat, const float* __restrict__ pos,
    const int* __restrict__ tokens,
    const float* __restrict__ Wq, const float* __restrict__ Wk,
    const float* __restrict__ Wg, const float* __restrict__ bg,
    ushort* __restrict__ fbf, ushort* __restrict__ Wbf,
    float* __restrict__ gout, int* __restrict__ nvout) {
  const int bid = blockIdx.x;
  const int tid = threadIdx.x;

  if (bid < 1024) {
    // ---- prep_fg
    __shared__ __align__(16) float Ws[8192];  // 8 x 1024 fp32 = 32 KB
#pragma unroll
    for (int u = 0; u < 8; ++u)
      ((float4*)Ws)[u * 256 + tid] = ((const float4*)Wg)[u * 256 + tid];
    __syncthreads();

    const int w = tid >> 6, l = tid & 63;
    const int c0 = l * 16;
    const int row0 = bid * 8 + w * 2;

    float4 f[2][4];
#pragma unroll
    for (int r = 0; r < 2; ++r) {
      const int row = row0 + r;
      const float* src = (c0 < 512) ? (feat + (size_t)row * 512 + c0)
                                    : (pos + (size_t)row * 512 + (c0 - 512));
#pragma unroll
      for (int q4 = 0; q4 < 4; ++q4) f[r][q4] = *(const float4*)(src + q4 * 4);
      uint4 o0, o1;
      o0.x = pack2(f[r][0].x, f[r][0].y); o0.y = pack2(f[r][0].z, f[r][0].w);
      o0.z = pack2(f[r][1].x, f[r][1].y); o0.w = pack2(f[r][1].z, f[r][1].w);
      o1.x = pack2(f[r][2].x, f[r][2].y); o1.y = pack2(f[r][2].z, f[r][2].w);
      o1.z = pack2(f[r][3].x, f[r][3].y); o1.w = pack2(f[r][3].z, f[r][3].w);
      *(uint4*)(fbf + (size_t)row * 1024 + c0) = o0;
      *(uint4*)(fbf + (size_t)row * 1024 + c0 + 8) = o1;
    }

    float s[2][8];
#pragma unroll
    for (int h = 0; h < 8; ++h) {
      const float* wg = Ws + h * 1024 + c0;
      float4 w0 = *(const float4*)(wg + 0);
      float4 w1 = *(const float4*)(wg + 4);
      float4 w2 = *(const float4*)(wg + 8);
      float4 w3 = *(const float4*)(wg + 12);
#pragma unroll
      for (int r = 0; r < 2; ++r)
        s[r][h] = f[r][0].x * w0.x + f[r][0].y * w0.y + f[r][0].z * w0.z + f[r][0].w * w0.w
                + f[r][1].x * w1.x + f[r][1].y * w1.y + f[r][1].z * w1.z + f[r][1].w * w1.w
                + f[r][2].x * w2.x + f[r][2].y * w2.y + f[r][2].z * w2.z + f[r][2].w * w2.w
                + f[r][3].x * w3.x + f[r][3].y * w3.y + f[r][3].z * w3.z + f[r][3].w * w3.w;
    }
#pragma unroll
    for (int m = 1; m < 64; m <<= 1)
#pragma unroll
      for (int r = 0; r < 2; ++r)
#pragma unroll
        for (int h = 0; h < 8; ++h) s[r][h] += __shfl_xor(s[r][h], m, 64);
    if (l == 0) {
#pragma unroll
      for (int r = 0; r < 2; ++r) {
        float lg[8], mx = -1e30f;
#pragma unroll
        for (int h = 0; h < 8; ++h) { lg[h] = s[r][h] + bg[h]; mx = fmaxf(mx, lg[h]); }
        float sum = 0.f;
#pragma unroll
        for (int h = 0; h < 8; ++h) sum += __expf(lg[h] - mx);
        const float lse = mx + __logf(sum);
#pragma unroll
        for (int h = 0; h < 8; ++h) gout[(size_t)(row0 + r) * 8 + h] = lg[h] - lse;
      }
    }
  } else if (bid < 1536) {
    // ---- prep_w
    const int gid = (bid - 1024) * 256 + tid;  // 0..131071
    const int e0 = gid * 8;
    const int n = e0 >> 10, k = e0 & 1023;
    const float* src = (n < 512) ? (Wq + (size_t)n * 1024 + k)
                                 : (Wk + (size_t)(n - 512) * 1024 + k);
    float4 a = *(const float4*)src;
    float4 b = *(const float4*)(src + 4);
    uint4 o;
    o.x = pack2(a.x, a.y); o.y = pack2(a.z, a.w);
    o.z = pack2(b.x, b.y); o.w = pack2(b.z, b.w);
    *(uint4*)(Wbf + (size_t)n * 1024 + k) = o;
  } else {
    // ---- n_valid
    const int b = bid - 1536;
    int cnt = 0;
    for (int i = tid; i < T; i += 256) cnt += (tokens[b * T + i] != 0) ? 1 : 0;
    __shared__ int s[256];
    s[tid] = cnt;
    __syncthreads();
    for (int st = 128; st > 0; st >>= 1) {
      if (tid < st) s[tid] += s[tid + st];
      __syncthreads();
    }
    if (tid == 0) nvout[b] = s[0];
  }
}

// ---------------------------------------------------------------- fused q/k GEMM
// 128x128 tile, BK=64, 2-phase prefetch double-buffer, swapped-operand MFMA,
// XCD-chunked swizzle.
__global__ __launch_bounds__(256) void k_gemm(
    const ushort* __restrict__ fbf, const ushort* __restrict__ Wbf,
    const float* __restrict__ bq, const float* __restrict__ bk,
    ushort* __restrict__ qbuf, ushort* __restrict__ kbuf) {
  const int g = blockIdx.x + 8 * blockIdx.y;   // dispatch-linear id; xcd ~ g%8
  const int wid = (g & 7) * 64 + (g >> 3);     // bijective (512 = 8*64)
  const int n0 = (wid & 7) * 128;
  const int m0 = (wid >> 3) * 128;
  const int tid = threadIdx.x;
  const int w = tid >> 6, l = tid & 63;
  const int lo = l & 15, quad = l >> 4;
  const int wm0 = (w >> 1) * 64, wn0 = (w & 1) * 64;

  __shared__ ushort As[2][128 * 64];  // 2 x 16 KB, linear row-major [128][64]
  __shared__ ushort Bs[2][128 * 64];

  f32x4 acc[4][4];
#pragma unroll
  for (int i = 0; i < 4; ++i)
#pragma unroll
    for (int j = 0; j < 4; ++j) acc[i][j] = (f32x4){0.f, 0.f, 0.f, 0.f};

  const int c8 = (tid & 7) * 8;
  const int r0 = tid >> 3;

  auto stage = [&](int buf, int k0) {
#pragma unroll
    for (int u = 0; u < 4; ++u) {
      gl_lds16(fbf + (size_t)(m0 + u * 32 + r0) * 1024 + k0 + c8,
               As[buf] + (size_t)w * 512 + u * 2048);
      gl_lds16(Wbf + (size_t)(n0 + u * 32 + r0) * 1024 + k0 + c8,
               Bs[buf] + (size_t)w * 512 + u * 2048);
    }
  };

  stage(0, 0);
  int cur = 0;
  for (int k0 = 0; k0 < 1024; k0 += 64) {
    __syncthreads();  // drains vmcnt: buf[cur] staged; buf[cur^1] readers done
    if (k0 + 64 < 1024) stage(cur ^ 1, k0 + 64);  // in flight during compute
    const ushort* pA = As[cur];
    const ushort* pB = Bs[cur];
#pragma unroll
    for (int kk = 0; kk < 2; ++kk) {
      short8 af[4], bfr[4];
#pragma unroll
      for (int mi = 0; mi < 4; ++mi)
        af[mi] = *(const short8*)(pA + (size_t)(wm0 + mi * 16 + lo) * 64 + kk * 32 + quad * 8);
#pragma unroll
      for (int ni = 0; ni < 4; ++ni)
        bfr[ni] = *(const short8*)(pB + (size_t)(wn0 + ni * 16 + lo) * 64 + kk * 32 + quad * 8);
#pragma unroll
      for (int mi = 0; mi < 4; ++mi)
#pragma unroll
        for (int ni = 0; ni < 4; ++ni)  // swapped: rows=n, cols=m
          acc[mi][ni] = __builtin_amdgcn_mfma_f32_16x16x32_bf16(bfr[ni], af[mi], acc[mi][ni], 0, 0, 0);
    }
    cur ^= 1;
  }

  // epilogue: lane owns row m, 4 consecutive n per (ni)
  float4 bias4[4];
#pragma unroll
  for (int ni = 0; ni < 4; ++ni) {
    const int gn = n0 + wn0 + ni * 16 + quad * 4;
    bias4[ni] = *(const float4*)((gn < 512) ? (bq + gn) : (bk + gn - 512));
  }
#pragma unroll
  for (int mi = 0; mi < 4; ++mi) {
    const int m = m0 + wm0 + mi * 16 + lo;
#pragma unroll
    for (int ni = 0; ni < 4; ++ni) {
      const int gn = n0 + wn0 + ni * 16 + quad * 4;
      ushort* dst = (gn < 512) ? (qbuf + (size_t)m * 512 + gn)
                               : (kbuf + (size_t)m * 512 + gn - 512);
      ushort4 o;
      o.x = f2bf(acc[mi][ni][0] + bias4[ni].x);
      o.y = f2bf(acc[mi][ni][1] + bias4[ni].y);
      o.z = f2bf(acc[mi][ni][2] + bias4[ni].z);
      o.w = f2bf(acc[mi][ni][3] + bias4[ni].w);
      *(ushort4*)dst = o;
    }
  }
}

// ---------------------------------------------------------------- pass1 (unchanged)
// K dbuf LDS, swapped 16x16 MFMA, maskless interior tiles.
__global__ __launch_bounds__(256) void k_pass1(
    const ushort* __restrict__ q, const ushort* __restrict__ kv,
    const float* __restrict__ g, const int* __restrict__ nvp,
    float* __restrict__ Wt) {
  const int it = blockIdx.x, h = blockIdx.y, b = blockIdx.z;
  const int nv = nvp[b];
  const int i0 = it * 64;
  const int tid = threadIdx.x;
  const int w = tid >> 6, l = tid & 63;
  const int lo = l & 15, quad = l >> 4;

  __shared__ ushort Ks[2][64 * 64];  // 2 x 8 KB

  const int i = i0 + w * 16 + lo;
  const ushort* qp = q + (size_t)(b * T + i) * 512 + h * 64 + quad * 8;
  const short8 a0 = *(const short8*)qp;
  const short8 a1 = *(const short8*)(qp + 32);

  float lsum = 0.f;
  const int ntile = ((nv + 63) >> 6) - it;

  if (ntile > 0) {
    auto stage = [&](int buf, int jt) {
#pragma unroll
      for (int u = 0; u < 2; ++u) {
        const int s = u * 256 + tid;
        const int row = s >> 3, c = s & 7;
        gl_lds16(kv + (size_t)(b * T + jt * 64 + row) * 512 + h * 64 + ((c ^ (row & 7)) * 8),
                 Ks[buf] + (size_t)(u * 256 + w * 64) * 8);
      }
    };
    stage(0, it);
    __syncthreads();
    for (int s = 0; s < ntile; ++s) {
      if (s + 1 < ntile) stage((s + 1) & 1, it + s + 1);
      const ushort* kbase = Ks[s & 1];
      const int j0 = (it + s) * 64;
      const bool diag = (s == 0);
      const bool masked = diag | (j0 + 64 > nv);
#pragma unroll
      for (int ni = 0; ni < 4; ++ni) {
        if (diag && ni < w) continue;  // sub-tile fully below diagonal (wave-uniform)
        const int rw = ni * 16 + lo;
        const short8 b0 = *(const short8*)(kbase + (size_t)rw * 64 + ((quad ^ (rw & 7)) * 8));
        const short8 b1 = *(const short8*)(kbase + (size_t)rw * 64 + (((4 + quad) ^ (rw & 7)) * 8));
        f32x4 acc = (f32x4){0.f, 0.f, 0.f, 0.f};
        acc = __builtin_amdgcn_mfma_f32_16x16x32_bf16(b0, a0, acc, 0, 0, 0);
        acc = __builtin_amdgcn_mfma_f32_16x16x32_bf16(b1, a1, acc, 0, 0, 0);
        if (!masked) {
#pragma unroll
          for (int r = 0; r < 4; ++r) lsum += __builtin_amdgcn_exp2f(acc[r] * SC);
        } else {
          const int jb = j0 + ni * 16 + quad * 4;
#pragma unroll
          for (int r = 0; r < 4; ++r) {
            const int j = jb + r;
            if (j > i && j < nv) lsum += __builtin_amdgcn_exp2f(acc[r] * SC);
          }
        }
      }
      __syncthreads();
    }
  }

  lsum += __shfl_xor(lsum, 16, 64);
  lsum += __shfl_xor(lsum, 32, 64);
  if (quad == 0) {
    const size_t row = (size_t)(b * T) + i;
    Wt[(size_t)h * NROW + row] =
        (lsum > 0.f) ? (g[row * 8 + h] - __logf(lsum)) : NEG_INF;
  }
}

// ---------------------------------------------------------------- pass2: per-head dbuf staging
// K tile per head = 8 KB, double-buffered (16 KB LDS -> 4 blocks/CU vs 2).
// stage(h+1) issued BEFORE computing head h (T3 2-phase). 16x16 swapped MFMA,
// r3-verified fragment layout + XOR swizzle (identical to pass1's, 0 conflicts).
__global__ __launch_bounds__(256) void k_pass2(
    const ushort* __restrict__ q, const ushort* __restrict__ kv,
    const float* __restrict__ Wt, const int* __restrict__ nvp,
    float* __restrict__ out) {
  const int jt = blockIdx.x, it = blockIdx.y, b = blockIdx.z;
  const int nv = nvp[b];
  const int i0 = it * 64, j0 = jt * 64;
  const int tid = threadIdx.x;

  if (jt < it || j0 >= nv) {
    const int r0 = tid >> 4, c0 = (tid & 15) * 4;
    float4 v; v.x = v.y = v.z = v.w = SENT;
#pragma unroll
    for (int u = 0; u < 4; ++u)
      *(float4*)(out + ((size_t)(b * T + i0 + r0 + u * 16)) * T + j0 + c0) = v;
    return;
  }

  const int w = tid >> 6, l = tid & 63;
  const int lo = l & 15, quad = l >> 4;
  const int i = i0 + w * 16 + lo;

  __shared__ ushort Ks[2][64 * 64];  // 2 x 8 KB

  auto stage = [&](int buf, int h) {
#pragma unroll
    for (int u = 0; u < 2; ++u) {
      const int s = u * 256 + tid;
      const int row = s >> 3, c = s & 7;
      gl_lds16(kv + (size_t)(b * T + j0 + row) * 512 + h * 64 + ((c ^ (row & 7)) * 8),
               Ks[buf] + (size_t)(u * 256 + w * 64) * 8);
    }
  };

  stage(0, 0);  // head 0 in flight

  // Q fragments + per-row weights, all 8 heads (16 frags = 64 VGPR, r3-proven resident)
  const ushort* qb = q + (size_t)(b * T + i) * 512 + quad * 8;
  short8 qa0[8], qa1[8];
  float wl[8];
#pragma unroll
  for (int h = 0; h < 8; ++h) {
    qa0[h] = *(const short8*)(qb + h * 64);
    qa1[h] = *(const short8*)(qb + h * 64 + 32);
    wl[h] = Wt[(size_t)h * NROW + b * T + i] * LOG2E;  // -inf stays -inf
  }

  float se[4][4];  // [ni][r], r = j offset
#pragma unroll
  for (int a = 0; a < 4; ++a)
#pragma unroll
    for (int c = 0; c < 4; ++c) se[a][c] = 0.f;

  __syncthreads();  // head-0 staging complete

#pragma unroll
  for (int h = 0; h < 8; ++h) {
    if (h < 7) stage((h + 1) & 1, h + 1);  // prefetch next head under this head's compute
    const ushort* kbase = Ks[h & 1];
#pragma unroll
    for (int ni = 0; ni < 4; ++ni) {
      const int rw = ni * 16 + lo;
      const short8 b0 = *(const short8*)(kbase + (size_t)rw * 64 + ((quad ^ (rw & 7)) * 8));
      const short8 b1 = *(const short8*)(kbase + (size_t)rw * 64 + (((4 + quad) ^ (rw & 7)) * 8));
      f32x4 acc = (f32x4){0.f, 0.f, 0.f, 0.f};
      acc = __builtin_amdgcn_mfma_f32_16x16x32_bf16(b0, qa0[h], acc, 0, 0, 0);
      acc = __builtin_amdgcn_mfma_f32_16x16x32_bf16(b1, qa1[h], acc, 0, 0, 0);
#pragma unroll
      for (int r = 0; r < 4; ++r)
        se[ni][r] += __builtin_amdgcn_exp2f(acc[r] * SC + wl[h]);
    }
    if (h < 7) __syncthreads();  // next-head staging drained + buffer reuse safe
  }

  const size_t orow = ((size_t)(b * T + i)) * T;
#pragma unroll
  for (int ni = 0; ni < 4; ++ni) {
    const int jb = j0 + ni * 16 + quad * 4;
    float4 v;
    v.x = (jb + 0 > i && jb + 0 < nv) ? fmaxf(__logf(se[ni][0]), SENT) : SENT;
    v.y = (jb + 1 > i && jb + 1 < nv) ? fmaxf(__logf(se[ni][1]), SENT) : SENT;
    v.z = (jb + 2 > i && jb + 2 < nv) ? fmaxf(__logf(se[ni][2]), SENT) : SENT;
    v.w = (jb + 3 > i && jb + 3 < nv) ? fmaxf(__logf(se[ni][3]), SENT) : SENT;
    *(float4*)(out + orow + jb) = v;
  }
}

// ---------------------------------------------------------------- launch
extern "C" void kernel_launch(void* const* d_in, const int* in_sizes, int n_in,
                              void* d_out, int out_size, void* d_ws, size_t ws_size,
                              hipStream_t stream) {
  (void)in_sizes; (void)n_in; (void)out_size; (void)ws_size;
  const float* feat = (const float*)d_in[0];
  const float* pos  = (const float*)d_in[1];
  const int* tokens = (const int*)d_in[2];
  const float* Wq = (const float*)d_in[3];
  const float* bq = (const float*)d_in[4];
  const float* Wk = (const float*)d_in[5];
  const float* bk = (const float*)d_in[6];
  const float* Wg = (const float*)d_in[7];
  const float* bg = (const float*)d_in[8];
  float* out = (float*)d_out;

  // workspace: qbuf 8.4M | kbuf 8.4M | Wbf 2M | gbuf 256K | Wt 256K | nv
  ushort* qbuf = (ushort*)d_ws;
  ushort* kbuf = qbuf + (size_t)NROW * 512;
  ushort* Wbf  = kbuf + (size_t)NROW * 512;
  float*  gbuf = (float*)(Wbf + (size_t)1024 * 1024);
  float*  Wt   = gbuf + (size_t)NROW * NH;
  int*    nv   = (int*)(Wt + (size_t)NH * NROW);

  // fbf (bf16 concat of feat,pos) lives in d_out; consumed by k_gemm,
  // fully overwritten later by k_pass2.
  ushort* fbf = (ushort*)d_out;

  k_prep<<<dim3(1544), dim3(256), 0, stream>>>(feat, pos, tokens, Wq, Wk, Wg, bg,
                                               fbf, Wbf, gbuf, nv);
  k_gemm<<<dim3(8, 64), dim3(256), 0, stream>>>(fbf, Wbf, bq, bk, qbuf, kbuf);
  k_pass1<<<dim3(16, NH, BATCH), dim3(256), 0, stream>>>(qbuf, kbuf, gbuf, nv, Wt);
  k_pass2<<<dim3(16, 16, BATCH), dim3(256), 0, stream>>>(qbuf, kbuf, Wt, nv, out);
}

// Round 6
// 165.821 us; speedup vs baseline: 1.1724x; 1.1003x over previous
//
#include <hip/hip_runtime.h>
#include <math.h>

#define BATCH 8
#define T 1024
#define NH 8
#define NROW 8192
#define NEG_INF (-INFINITY)
#define SENT (-1.0e30f)
#define SC 0.180336880f      // 0.125 * log2(e)
#define LOG2E 1.442695041f

typedef __attribute__((ext_vector_type(8))) short short8;    // 8 bf16 (4 VGPRs)
typedef __attribute__((ext_vector_type(4))) float f32x4;

// fp32 -> bf16 (RNE)
__device__ __forceinline__ ushort f2bf(float x) {
  uint u = __float_as_uint(x);
  return (ushort)((u + 0x7FFFu + ((u >> 16) & 1u)) >> 16);
}
__device__ __forceinline__ uint pack2(float a, float b) {
  return (uint)f2bf(a) | ((uint)f2bf(b) << 16);
}
// async global->LDS, 16B per lane; LDS dest = wave-uniform base + lane*16
__device__ __forceinline__ void gl_lds16(const ushort* g, ushort* l) {
  __builtin_amdgcn_global_load_lds(
      (const __attribute__((address_space(1))) unsigned int*)g,
      (__attribute__((address_space(3))) unsigned int*)l, 16, 0, 0);
}

// ---------------------------------------------------------------- merged prep
// blocks [0,1024): prep_fg (bf16 pack + gate log-softmax)
// blocks [1024,1536): prep_w (Wq/Wk -> bf16 concat)
// blocks [1536,1544): n_valid
__global__ __launch_bounds__(256) void k_prep(
    const float* __restrict__ feat, const float* __restrict__ pos,
    const int* __restrict__ tokens,
    const float* __restrict__ Wq, const float* __restrict__ Wk,
    const float* __restrict__ Wg, const float* __restrict__ bg,
    ushort* __restrict__ fbf, ushort* __restrict__ Wbf,
    float* __restrict__ gout, int* __restrict__ nvout) {
  const int bid = blockIdx.x;
  const int tid = threadIdx.x;

  if (bid < 1024) {
    // ---- prep_fg
    __shared__ __align__(16) float Ws[8192];  // 8 x 1024 fp32 = 32 KB
#pragma unroll
    for (int u = 0; u < 8; ++u)
      ((float4*)Ws)[u * 256 + tid] = ((const float4*)Wg)[u * 256 + tid];
    __syncthreads();

    const int w = tid >> 6, l = tid & 63;
    const int c0 = l * 16;
    const int row0 = bid * 8 + w * 2;

    float4 f[2][4];
#pragma unroll
    for (int r = 0; r < 2; ++r) {
      const int row = row0 + r;
      const float* src = (c0 < 512) ? (feat + (size_t)row * 512 + c0)
                                    : (pos + (size_t)row * 512 + (c0 - 512));
#pragma unroll
      for (int q4 = 0; q4 < 4; ++q4) f[r][q4] = *(const float4*)(src + q4 * 4);
      uint4 o0, o1;
      o0.x = pack2(f[r][0].x, f[r][0].y); o0.y = pack2(f[r][0].z, f[r][0].w);
      o0.z = pack2(f[r][1].x, f[r][1].y); o0.w = pack2(f[r][1].z, f[r][1].w);
      o1.x = pack2(f[r][2].x, f[r][2].y); o1.y = pack2(f[r][2].z, f[r][2].w);
      o1.z = pack2(f[r][3].x, f[r][3].y); o1.w = pack2(f[r][3].z, f[r][3].w);
      *(uint4*)(fbf + (size_t)row * 1024 + c0) = o0;
      *(uint4*)(fbf + (size_t)row * 1024 + c0 + 8) = o1;
    }

    float s[2][8];
#pragma unroll
    for (int h = 0; h < 8; ++h) {
      const float* wg = Ws + h * 1024 + c0;
      float4 w0 = *(const float4*)(wg + 0);
      float4 w1 = *(const float4*)(wg + 4);
      float4 w2 = *(const float4*)(wg + 8);
      float4 w3 = *(const float4*)(wg + 12);
#pragma unroll
      for (int r = 0; r < 2; ++r)
        s[r][h] = f[r][0].x * w0.x + f[r][0].y * w0.y + f[r][0].z * w0.z + f[r][0].w * w0.w
                + f[r][1].x * w1.x + f[r][1].y * w1.y + f[r][1].z * w1.z + f[r][1].w * w1.w
                + f[r][2].x * w2.x + f[r][2].y * w2.y + f[r][2].z * w2.z + f[r][2].w * w2.w
                + f[r][3].x * w3.x + f[r][3].y * w3.y + f[r][3].z * w3.z + f[r][3].w * w3.w;
    }
#pragma unroll
    for (int m = 1; m < 64; m <<= 1)
#pragma unroll
      for (int r = 0; r < 2; ++r)
#pragma unroll
        for (int h = 0; h < 8; ++h) s[r][h] += __shfl_xor(s[r][h], m, 64);
    if (l == 0) {
#pragma unroll
      for (int r = 0; r < 2; ++r) {
        float lg[8], mx = -1e30f;
#pragma unroll
        for (int h = 0; h < 8; ++h) { lg[h] = s[r][h] + bg[h]; mx = fmaxf(mx, lg[h]); }
        float sum = 0.f;
#pragma unroll
        for (int h = 0; h < 8; ++h) sum += __expf(lg[h] - mx);
        const float lse = mx + __logf(sum);
#pragma unroll
        for (int h = 0; h < 8; ++h) gout[(size_t)(row0 + r) * 8 + h] = lg[h] - lse;
      }
    }
  } else if (bid < 1536) {
    // ---- prep_w
    const int gid = (bid - 1024) * 256 + tid;  // 0..131071
    const int e0 = gid * 8;
    const int n = e0 >> 10, k = e0 & 1023;
    const float* src = (n < 512) ? (Wq + (size_t)n * 1024 + k)
                                 : (Wk + (size_t)(n - 512) * 1024 + k);
    float4 a = *(const float4*)src;
    float4 b = *(const float4*)(src + 4);
    uint4 o;
    o.x = pack2(a.x, a.y); o.y = pack2(a.z, a.w);
    o.z = pack2(b.x, b.y); o.w = pack2(b.z, b.w);
    *(uint4*)(Wbf + (size_t)n * 1024 + k) = o;
  } else {
    // ---- n_valid
    const int b = bid - 1536;
    int cnt = 0;
    for (int i = tid; i < T; i += 256) cnt += (tokens[b * T + i] != 0) ? 1 : 0;
    __shared__ int s[256];
    s[tid] = cnt;
    __syncthreads();
    for (int st = 128; st > 0; st >>= 1) {
      if (tid < st) s[tid] += s[tid + st];
      __syncthreads();
    }
    if (tid == 0) nvout[b] = s[0];
  }
}

// ---------------------------------------------------------------- fused q/k GEMM (unchanged)
__global__ __launch_bounds__(256) void k_gemm(
    const ushort* __restrict__ fbf, const ushort* __restrict__ Wbf,
    const float* __restrict__ bq, const float* __restrict__ bk,
    ushort* __restrict__ qbuf, ushort* __restrict__ kbuf) {
  const int g = blockIdx.x + 8 * blockIdx.y;   // dispatch-linear id; xcd ~ g%8
  const int wid = (g & 7) * 64 + (g >> 3);     // bijective (512 = 8*64)
  const int n0 = (wid & 7) * 128;
  const int m0 = (wid >> 3) * 128;
  const int tid = threadIdx.x;
  const int w = tid >> 6, l = tid & 63;
  const int lo = l & 15, quad = l >> 4;
  const int wm0 = (w >> 1) * 64, wn0 = (w & 1) * 64;

  __shared__ ushort As[2][128 * 64];  // 2 x 16 KB, linear row-major [128][64]
  __shared__ ushort Bs[2][128 * 64];

  f32x4 acc[4][4];
#pragma unroll
  for (int i = 0; i < 4; ++i)
#pragma unroll
    for (int j = 0; j < 4; ++j) acc[i][j] = (f32x4){0.f, 0.f, 0.f, 0.f};

  const int c8 = (tid & 7) * 8;
  const int r0 = tid >> 3;

  auto stage = [&](int buf, int k0) {
#pragma unroll
    for (int u = 0; u < 4; ++u) {
      gl_lds16(fbf + (size_t)(m0 + u * 32 + r0) * 1024 + k0 + c8,
               As[buf] + (size_t)w * 512 + u * 2048);
      gl_lds16(Wbf + (size_t)(n0 + u * 32 + r0) * 1024 + k0 + c8,
               Bs[buf] + (size_t)w * 512 + u * 2048);
    }
  };

  stage(0, 0);
  int cur = 0;
  for (int k0 = 0; k0 < 1024; k0 += 64) {
    __syncthreads();  // drains vmcnt: buf[cur] staged; buf[cur^1] readers done
    if (k0 + 64 < 1024) stage(cur ^ 1, k0 + 64);  // in flight during compute
    const ushort* pA = As[cur];
    const ushort* pB = Bs[cur];
#pragma unroll
    for (int kk = 0; kk < 2; ++kk) {
      short8 af[4], bfr[4];
#pragma unroll
      for (int mi = 0; mi < 4; ++mi)
        af[mi] = *(const short8*)(pA + (size_t)(wm0 + mi * 16 + lo) * 64 + kk * 32 + quad * 8);
#pragma unroll
      for (int ni = 0; ni < 4; ++ni)
        bfr[ni] = *(const short8*)(pB + (size_t)(wn0 + ni * 16 + lo) * 64 + kk * 32 + quad * 8);
#pragma unroll
      for (int mi = 0; mi < 4; ++mi)
#pragma unroll
        for (int ni = 0; ni < 4; ++ni)  // swapped: rows=n, cols=m
          acc[mi][ni] = __builtin_amdgcn_mfma_f32_16x16x32_bf16(bfr[ni], af[mi], acc[mi][ni], 0, 0, 0);
    }
    cur ^= 1;
  }

  // epilogue: lane owns row m, 4 consecutive n per (ni)
  float4 bias4[4];
#pragma unroll
  for (int ni = 0; ni < 4; ++ni) {
    const int gn = n0 + wn0 + ni * 16 + quad * 4;
    bias4[ni] = *(const float4*)((gn < 512) ? (bq + gn) : (bk + gn - 512));
  }
#pragma unroll
  for (int mi = 0; mi < 4; ++mi) {
    const int m = m0 + wm0 + mi * 16 + lo;
#pragma unroll
    for (int ni = 0; ni < 4; ++ni) {
      const int gn = n0 + wn0 + ni * 16 + quad * 4;
      ushort* dst = (gn < 512) ? (qbuf + (size_t)m * 512 + gn)
                               : (kbuf + (size_t)m * 512 + gn - 512);
      ushort4 o;
      o.x = f2bf(acc[mi][ni][0] + bias4[ni].x);
      o.y = f2bf(acc[mi][ni][1] + bias4[ni].y);
      o.z = f2bf(acc[mi][ni][2] + bias4[ni].z);
      o.w = f2bf(acc[mi][ni][3] + bias4[ni].w);
      *(ushort4*)dst = o;
    }
  }
}

// ---------------------------------------------------------------- pass1
// Body unchanged (verified); grid reordered so blockIdx.x = b -> XCD = b
// (per-XCD working set = one batch's q/k = 2 MB, fits the 4 MB XCD L2).
__global__ __launch_bounds__(256) void k_pass1(
    const ushort* __restrict__ q, const ushort* __restrict__ kv,
    const float* __restrict__ g, const int* __restrict__ nvp,
    float* __restrict__ Wt) {
  const int b = blockIdx.x, h = blockIdx.y, it = blockIdx.z;
  const int nv = nvp[b];
  const int i0 = it * 64;
  const int tid = threadIdx.x;
  const int w = tid >> 6, l = tid & 63;
  const int lo = l & 15, quad = l >> 4;

  __shared__ ushort Ks[2][64 * 64];  // 2 x 8 KB

  const int i = i0 + w * 16 + lo;
  const ushort* qp = q + (size_t)(b * T + i) * 512 + h * 64 + quad * 8;
  const short8 a0 = *(const short8*)qp;
  const short8 a1 = *(const short8*)(qp + 32);

  float lsum = 0.f;
  const int ntile = ((nv + 63) >> 6) - it;

  if (ntile > 0) {
    auto stage = [&](int buf, int jt) {
#pragma unroll
      for (int u = 0; u < 2; ++u) {
        const int s = u * 256 + tid;
        const int row = s >> 3, c = s & 7;
        gl_lds16(kv + (size_t)(b * T + jt * 64 + row) * 512 + h * 64 + ((c ^ (row & 7)) * 8),
                 Ks[buf] + (size_t)(u * 256 + w * 64) * 8);
      }
    };
    stage(0, it);
    __syncthreads();
    for (int s = 0; s < ntile; ++s) {
      if (s + 1 < ntile) stage((s + 1) & 1, it + s + 1);
      const ushort* kbase = Ks[s & 1];
      const int j0 = (it + s) * 64;
      const bool diag = (s == 0);
      const bool masked = diag | (j0 + 64 > nv);
#pragma unroll
      for (int ni = 0; ni < 4; ++ni) {
        if (diag && ni < w) continue;  // sub-tile fully below diagonal (wave-uniform)
        const int rw = ni * 16 + lo;
        const short8 b0 = *(const short8*)(kbase + (size_t)rw * 64 + ((quad ^ (rw & 7)) * 8));
        const short8 b1 = *(const short8*)(kbase + (size_t)rw * 64 + (((4 + quad) ^ (rw & 7)) * 8));
        f32x4 acc = (f32x4){0.f, 0.f, 0.f, 0.f};
        acc = __builtin_amdgcn_mfma_f32_16x16x32_bf16(b0, a0, acc, 0, 0, 0);
        acc = __builtin_amdgcn_mfma_f32_16x16x32_bf16(b1, a1, acc, 0, 0, 0);
        if (!masked) {
#pragma unroll
          for (int r = 0; r < 4; ++r) lsum += __builtin_amdgcn_exp2f(acc[r] * SC);
        } else {
          const int jb = j0 + ni * 16 + quad * 4;
#pragma unroll
          for (int r = 0; r < 4; ++r) {
            const int j = jb + r;
            if (j > i && j < nv) lsum += __builtin_amdgcn_exp2f(acc[r] * SC);
          }
        }
      }
      __syncthreads();
    }
  }

  lsum += __shfl_xor(lsum, 16, 64);
  lsum += __shfl_xor(lsum, 32, 64);
  if (quad == 0) {
    const size_t row = (size_t)(b * T) + i;
    Wt[(size_t)h * NROW + row] =
        (lsum > 0.f) ? (g[row * 8 + h] - __logf(lsum)) : NEG_INF;
  }
}

// ---------------------------------------------------------------- pass2: 128x128 tiles, 8 waves
// Q and K both LDS-staged per head (16 KB each), double-buffered (64 KB), 2-phase
// prefetch (stage h+1 before compute h). blockIdx.x = b -> XCD-local L2 (2 MB/batch).
// Traffic: 288 interior blocks x 256 KB = 74 MB (was 139 MB at 64x64 tiles).
__global__ __launch_bounds__(512) void k_pass2(
    const ushort* __restrict__ q, const ushort* __restrict__ kv,
    const float* __restrict__ Wt, const int* __restrict__ nvp,
    float* __restrict__ out) {
  const int b = blockIdx.x, jt = blockIdx.y, it = blockIdx.z;
  const int nv = nvp[b];
  const int i0 = it * 128, j0 = jt * 128;
  const int tid = threadIdx.x;

  if (jt < it || j0 >= nv) {
    const int r0 = tid >> 5, c0 = (tid & 31) * 4;
    float4 v; v.x = v.y = v.z = v.w = SENT;
#pragma unroll
    for (int u = 0; u < 8; ++u)
      *(float4*)(out + ((size_t)(b * T + i0 + r0 + u * 16)) * T + j0 + c0) = v;
    return;
  }

  const int w = tid >> 6, l = tid & 63;
  const int lo = l & 15, quad = l >> 4;
  const int qi = w & 3, qj = w >> 2;  // wave tile: i = qi*32..+32, j = qj*64..+64

  __shared__ ushort Qs[2][128 * 64];  // 2 x 16 KB
  __shared__ ushort Ks[2][128 * 64];  // 2 x 16 KB

  auto stage = [&](int buf, int h) {
#pragma unroll
    for (int u = 0; u < 2; ++u) {
      const int s = u * 512 + tid;        // 0..1023 chunk id
      const int row = s >> 3, c = s & 7;  // row 0..127, chunk 0..7
      gl_lds16(q  + (size_t)(b * T + i0 + row) * 512 + h * 64 + ((c ^ (row & 7)) * 8),
               Qs[buf] + (size_t)(u * 512 + w * 64) * 8);
      gl_lds16(kv + (size_t)(b * T + j0 + row) * 512 + h * 64 + ((c ^ (row & 7)) * 8),
               Ks[buf] + (size_t)(u * 512 + w * 64) * 8);
    }
  };

  stage(0, 0);  // head 0 in flight

  // per-row gate/denominator weights for this wave's 2 i-frags (16 scalars)
  float wl[2][8];
#pragma unroll
  for (int mi = 0; mi < 2; ++mi) {
    const int i = i0 + qi * 32 + mi * 16 + lo;
#pragma unroll
    for (int h = 0; h < 8; ++h)
      wl[mi][h] = Wt[(size_t)h * NROW + b * T + i] * LOG2E;  // -inf stays -inf
  }

  float se[2][4][4];  // [mi][ni][r]
#pragma unroll
  for (int a = 0; a < 2; ++a)
#pragma unroll
    for (int c = 0; c < 4; ++c)
#pragma unroll
      for (int r = 0; r < 4; ++r) se[a][c][r] = 0.f;

  __syncthreads();  // head-0 staging complete

#pragma unroll
  for (int h = 0; h < 8; ++h) {
    if (h < 7) stage((h + 1) & 1, h + 1);  // prefetch next head under this compute
    const ushort* Qb = Qs[h & 1];
    const ushort* Kb = Ks[h & 1];
    f32x4 acc[2][4];
#pragma unroll
    for (int mi = 0; mi < 2; ++mi)
#pragma unroll
      for (int ni = 0; ni < 4; ++ni) acc[mi][ni] = (f32x4){0.f, 0.f, 0.f, 0.f};
#pragma unroll
    for (int kk = 0; kk < 2; ++kk) {
      const int swz = ((kk * 4 + quad) ^ (lo & 7)) * 8;  // row&7 == lo&7 (offsets %8==0)
      short8 qf[2], kf[4];
#pragma unroll
      for (int mi = 0; mi < 2; ++mi)
        qf[mi] = *(const short8*)(Qb + (size_t)(qi * 32 + mi * 16 + lo) * 64 + swz);
#pragma unroll
      for (int ni = 0; ni < 4; ++ni)
        kf[ni] = *(const short8*)(Kb + (size_t)(qj * 64 + ni * 16 + lo) * 64 + swz);
#pragma unroll
      for (int mi = 0; mi < 2; ++mi)
#pragma unroll
        for (int ni = 0; ni < 4; ++ni)
          acc[mi][ni] = __builtin_amdgcn_mfma_f32_16x16x32_bf16(kf[ni], qf[mi], acc[mi][ni], 0, 0, 0);
    }
#pragma unroll
    for (int mi = 0; mi < 2; ++mi)
#pragma unroll
      for (int ni = 0; ni < 4; ++ni)
#pragma unroll
        for (int r = 0; r < 4; ++r)
          se[mi][ni][r] += __builtin_amdgcn_exp2f(acc[mi][ni][r] * SC + wl[mi][h]);
    if (h < 7) __syncthreads();  // next-head staging drained + buffer reuse safe
  }

  // epilogue: lane owns row i; per (ni) 4 consecutive j -> float4 stores
#pragma unroll
  for (int mi = 0; mi < 2; ++mi) {
    const int i = i0 + qi * 32 + mi * 16 + lo;
    const size_t orow = ((size_t)(b * T + i)) * T;
#pragma unroll
    for (int ni = 0; ni < 4; ++ni) {
      const int jb = j0 + qj * 64 + ni * 16 + quad * 4;
      float4 v;
      v.x = (jb + 0 > i && jb + 0 < nv) ? fmaxf(__logf(se[mi][ni][0]), SENT) : SENT;
      v.y = (jb + 1 > i && jb + 1 < nv) ? fmaxf(__logf(se[mi][ni][1]), SENT) : SENT;
      v.z = (jb + 2 > i && jb + 2 < nv) ? fmaxf(__logf(se[mi][ni][2]), SENT) : SENT;
      v.w = (jb + 3 > i && jb + 3 < nv) ? fmaxf(__logf(se[mi][ni][3]), SENT) : SENT;
      *(float4*)(out + orow + jb) = v;
    }
  }
}

// ---------------------------------------------------------------- launch
extern "C" void kernel_launch(void* const* d_in, const int* in_sizes, int n_in,
                              void* d_out, int out_size, void* d_ws, size_t ws_size,
                              hipStream_t stream) {
  (void)in_sizes; (void)n_in; (void)out_size; (void)ws_size;
  const float* feat = (const float*)d_in[0];
  const float* pos  = (const float*)d_in[1];
  const int* tokens = (const int*)d_in[2];
  const float* Wq = (const float*)d_in[3];
  const float* bq = (const float*)d_in[4];
  const float* Wk = (const float*)d_in[5];
  const float* bk = (const float*)d_in[6];
  const float* Wg = (const float*)d_in[7];
  const float* bg = (const float*)d_in[8];
  float* out = (float*)d_out;

  // workspace: qbuf 8.4M | kbuf 8.4M | Wbf 2M | gbuf 256K | Wt 256K | nv
  ushort* qbuf = (ushort*)d_ws;
  ushort* kbuf = qbuf + (size_t)NROW * 512;
  ushort* Wbf  = kbuf + (size_t)NROW * 512;
  float*  gbuf = (float*)(Wbf + (size_t)1024 * 1024);
  float*  Wt   = gbuf + (size_t)NROW * NH;
  int*    nv   = (int*)(Wt + (size_t)NH * NROW);

  // fbf (bf16 concat of feat,pos) lives in d_out; consumed by k_gemm,
  // fully overwritten later by k_pass2.
  ushort* fbf = (ushort*)d_out;

  k_prep<<<dim3(1544), dim3(256), 0, stream>>>(feat, pos, tokens, Wq, Wk, Wg, bg,
                                               fbf, Wbf, gbuf, nv);
  k_gemm<<<dim3(8, 64), dim3(256), 0, stream>>>(fbf, Wbf, bq, bk, qbuf, kbuf);
  k_pass1<<<dim3(BATCH, NH, 16), dim3(256), 0, stream>>>(qbuf, kbuf, gbuf, nv, Wt);
  k_pass2<<<dim3(BATCH, 8, 8), dim3(512), 0, stream>>>(qbuf, kbuf, Wt, nv, out);
}

// Round 7
// 160.108 us; speedup vs baseline: 1.2142x; 1.0357x over previous
//
#include <hip/hip_runtime.h>
#include <math.h>

#define BATCH 8
#define T 1024
#define NH 8
#define NROW 8192
#define NEG_INF (-INFINITY)
#define SENT (-1.0e30f)
#define SC 0.180336880f      // 0.125 * log2(e)
#define LOG2E 1.442695041f

typedef __attribute__((ext_vector_type(8))) short short8;    // 8 bf16 (4 VGPRs)
typedef __attribute__((ext_vector_type(4))) float f32x4;

// fp32 -> bf16 (RNE)
__device__ __forceinline__ ushort f2bf(float x) {
  uint u = __float_as_uint(x);
  return (ushort)((u + 0x7FFFu + ((u >> 16) & 1u)) >> 16);
}
__device__ __forceinline__ uint pack2(float a, float b) {
  return (uint)f2bf(a) | ((uint)f2bf(b) << 16);
}
// async global->LDS, 16B per lane; LDS dest = wave-uniform base + lane*16
__device__ __forceinline__ void gl_lds16(const ushort* g, ushort* l) {
  __builtin_amdgcn_global_load_lds(
      (const __attribute__((address_space(1))) unsigned int*)g,
      (__attribute__((address_space(3))) unsigned int*)l, 16, 0, 0);
}

// ---------------------------------------------------------------- merged prep
// blocks [0,1024): prep_fg (bf16 pack + gate log-softmax)
// blocks [1024,1536): prep_w (Wq/Wk -> bf16 concat)
// blocks [1536,1544): n_valid
__global__ __launch_bounds__(256) void k_prep(
    const float* __restrict__ feat, const float* __restrict__ pos,
    const int* __restrict__ tokens,
    const float* __restrict__ Wq, const float* __restrict__ Wk,
    const float* __restrict__ Wg, const float* __restrict__ bg,
    ushort* __restrict__ fbf, ushort* __restrict__ Wbf,
    float* __restrict__ gout, int* __restrict__ nvout) {
  const int bid = blockIdx.x;
  const int tid = threadIdx.x;

  if (bid < 1024) {
    // ---- prep_fg
    __shared__ __align__(16) float Ws[8192];  // 8 x 1024 fp32 = 32 KB
#pragma unroll
    for (int u = 0; u < 8; ++u)
      ((float4*)Ws)[u * 256 + tid] = ((const float4*)Wg)[u * 256 + tid];
    __syncthreads();

    const int w = tid >> 6, l = tid & 63;
    const int c0 = l * 16;
    const int row0 = bid * 8 + w * 2;

    float4 f[2][4];
#pragma unroll
    for (int r = 0; r < 2; ++r) {
      const int row = row0 + r;
      const float* src = (c0 < 512) ? (feat + (size_t)row * 512 + c0)
                                    : (pos + (size_t)row * 512 + (c0 - 512));
#pragma unroll
      for (int q4 = 0; q4 < 4; ++q4) f[r][q4] = *(const float4*)(src + q4 * 4);
      uint4 o0, o1;
      o0.x = pack2(f[r][0].x, f[r][0].y); o0.y = pack2(f[r][0].z, f[r][0].w);
      o0.z = pack2(f[r][1].x, f[r][1].y); o0.w = pack2(f[r][1].z, f[r][1].w);
      o1.x = pack2(f[r][2].x, f[r][2].y); o1.y = pack2(f[r][2].z, f[r][2].w);
      o1.z = pack2(f[r][3].x, f[r][3].y); o1.w = pack2(f[r][3].z, f[r][3].w);
      *(uint4*)(fbf + (size_t)row * 1024 + c0) = o0;
      *(uint4*)(fbf + (size_t)row * 1024 + c0 + 8) = o1;
    }

    float s[2][8];
#pragma unroll
    for (int h = 0; h < 8; ++h) {
      const float* wg = Ws + h * 1024 + c0;
      float4 w0 = *(const float4*)(wg + 0);
      float4 w1 = *(const float4*)(wg + 4);
      float4 w2 = *(const float4*)(wg + 8);
      float4 w3 = *(const float4*)(wg + 12);
#pragma unroll
      for (int r = 0; r < 2; ++r)
        s[r][h] = f[r][0].x * w0.x + f[r][0].y * w0.y + f[r][0].z * w0.z + f[r][0].w * w0.w
                + f[r][1].x * w1.x + f[r][1].y * w1.y + f[r][1].z * w1.z + f[r][1].w * w1.w
                + f[r][2].x * w2.x + f[r][2].y * w2.y + f[r][2].z * w2.z + f[r][2].w * w2.w
                + f[r][3].x * w3.x + f[r][3].y * w3.y + f[r][3].z * w3.z + f[r][3].w * w3.w;
    }
#pragma unroll
    for (int m = 1; m < 64; m <<= 1)
#pragma unroll
      for (int r = 0; r < 2; ++r)
#pragma unroll
        for (int h = 0; h < 8; ++h) s[r][h] += __shfl_xor(s[r][h], m, 64);
    if (l == 0) {
#pragma unroll
      for (int r = 0; r < 2; ++r) {
        float lg[8], mx = -1e30f;
#pragma unroll
        for (int h = 0; h < 8; ++h) { lg[h] = s[r][h] + bg[h]; mx = fmaxf(mx, lg[h]); }
        float sum = 0.f;
#pragma unroll
        for (int h = 0; h < 8; ++h) sum += __expf(lg[h] - mx);
        const float lse = mx + __logf(sum);
#pragma unroll
        for (int h = 0; h < 8; ++h) gout[(size_t)(row0 + r) * 8 + h] = lg[h] - lse;
      }
    }
  } else if (bid < 1536) {
    // ---- prep_w
    const int gid = (bid - 1024) * 256 + tid;  // 0..131071
    const int e0 = gid * 8;
    const int n = e0 >> 10, k = e0 & 1023;
    const float* src = (n < 512) ? (Wq + (size_t)n * 1024 + k)
                                 : (Wk + (size_t)(n - 512) * 1024 + k);
    float4 a = *(const float4*)src;
    float4 b = *(const float4*)(src + 4);
    uint4 o;
    o.x = pack2(a.x, a.y); o.y = pack2(a.z, a.w);
    o.z = pack2(b.x, b.y); o.w = pack2(b.z, b.w);
    *(uint4*)(Wbf + (size_t)n * 1024 + k) = o;
  } else {
    // ---- n_valid
    const int b = bid - 1536;
    int cnt = 0;
    for (int i = tid; i < T; i += 256) cnt += (tokens[b * T + i] != 0) ? 1 : 0;
    __shared__ int s[256];
    s[tid] = cnt;
    __syncthreads();
    for (int st = 128; st > 0; st >>= 1) {
      if (tid < st) s[tid] += s[tid + st];
      __syncthreads();
    }
    if (tid == 0) nvout[b] = s[0];
  }
}

// ---------------------------------------------------------------- fused q/k GEMM
// 128x128 tile, BK=64, 2-phase prefetch dbuf, swapped-operand MFMA, XCD swizzle.
// NEW (r7): T2 XOR-chunk swizzle on As/Bs — linear [128][64] rows are 128 B
// stride => 16-way bank conflict on ds_read_b128. Source chunk pre-XOR'd
// (c ^ row&7) so LDS stays gl_lds-linear; read applies the same involution
// (pattern measured 0 conflicts in pass1/pass2, r2-r6).
__global__ __launch_bounds__(256) void k_gemm(
    const ushort* __restrict__ fbf, const ushort* __restrict__ Wbf,
    const float* __restrict__ bq, const float* __restrict__ bk,
    ushort* __restrict__ qbuf, ushort* __restrict__ kbuf) {
  const int g = blockIdx.x + 8 * blockIdx.y;   // dispatch-linear id; xcd ~ g%8
  const int wid = (g & 7) * 64 + (g >> 3);     // bijective (512 = 8*64)
  const int n0 = (wid & 7) * 128;
  const int m0 = (wid >> 3) * 128;
  const int tid = threadIdx.x;
  const int w = tid >> 6, l = tid & 63;
  const int lo = l & 15, quad = l >> 4;
  const int wm0 = (w >> 1) * 64, wn0 = (w & 1) * 64;

  __shared__ ushort As[2][128 * 64];  // 2 x 16 KB, linear row-major [128][64]
  __shared__ ushort Bs[2][128 * 64];

  f32x4 acc[4][4];
#pragma unroll
  for (int i = 0; i < 4; ++i)
#pragma unroll
    for (int j = 0; j < 4; ++j) acc[i][j] = (f32x4){0.f, 0.f, 0.f, 0.f};

  // lane's dest LDS row&7 == (tid>>3)&7; pre-swizzled source chunk:
  const int csw = ((tid & 7) ^ ((tid >> 3) & 7)) * 8;
  const int r0 = tid >> 3;

  auto stage = [&](int buf, int k0) {
#pragma unroll
    for (int u = 0; u < 4; ++u) {
      gl_lds16(fbf + (size_t)(m0 + u * 32 + r0) * 1024 + k0 + csw,
               As[buf] + (size_t)w * 512 + u * 2048);
      gl_lds16(Wbf + (size_t)(n0 + u * 32 + r0) * 1024 + k0 + csw,
               Bs[buf] + (size_t)w * 512 + u * 2048);
    }
  };

  stage(0, 0);
  int cur = 0;
  for (int k0 = 0; k0 < 1024; k0 += 64) {
    __syncthreads();  // drains vmcnt: buf[cur] staged; buf[cur^1] readers done
    if (k0 + 64 < 1024) stage(cur ^ 1, k0 + 64);  // in flight during compute
    const ushort* pA = As[cur];
    const ushort* pB = Bs[cur];
#pragma unroll
    for (int kk = 0; kk < 2; ++kk) {
      const int swz = ((kk * 4 + quad) ^ (lo & 7)) * 8;  // frag row&7 == lo&7
      short8 af[4], bfr[4];
#pragma unroll
      for (int mi = 0; mi < 4; ++mi)
        af[mi] = *(const short8*)(pA + (size_t)(wm0 + mi * 16 + lo) * 64 + swz);
#pragma unroll
      for (int ni = 0; ni < 4; ++ni)
        bfr[ni] = *(const short8*)(pB + (size_t)(wn0 + ni * 16 + lo) * 64 + swz);
#pragma unroll
      for (int mi = 0; mi < 4; ++mi)
#pragma unroll
        for (int ni = 0; ni < 4; ++ni)  // swapped: rows=n, cols=m
          acc[mi][ni] = __builtin_amdgcn_mfma_f32_16x16x32_bf16(bfr[ni], af[mi], acc[mi][ni], 0, 0, 0);
    }
    cur ^= 1;
  }

  // epilogue: lane owns row m, 4 consecutive n per (ni)
  float4 bias4[4];
#pragma unroll
  for (int ni = 0; ni < 4; ++ni) {
    const int gn = n0 + wn0 + ni * 16 + quad * 4;
    bias4[ni] = *(const float4*)((gn < 512) ? (bq + gn) : (bk + gn - 512));
  }
#pragma unroll
  for (int mi = 0; mi < 4; ++mi) {
    const int m = m0 + wm0 + mi * 16 + lo;
#pragma unroll
    for (int ni = 0; ni < 4; ++ni) {
      const int gn = n0 + wn0 + ni * 16 + quad * 4;
      ushort* dst = (gn < 512) ? (qbuf + (size_t)m * 512 + gn)
                               : (kbuf + (size_t)m * 512 + gn - 512);
      ushort4 o;
      o.x = f2bf(acc[mi][ni][0] + bias4[ni].x);
      o.y = f2bf(acc[mi][ni][1] + bias4[ni].y);
      o.z = f2bf(acc[mi][ni][2] + bias4[ni].z);
      o.w = f2bf(acc[mi][ni][3] + bias4[ni].w);
      *(ushort4*)dst = o;
    }
  }
}

// ---------------------------------------------------------------- pass1 (unchanged)
__global__ __launch_bounds__(256) void k_pass1(
    const ushort* __restrict__ q, const ushort* __restrict__ kv,
    const float* __restrict__ g, const int* __restrict__ nvp,
    float* __restrict__ Wt) {
  const int b = blockIdx.x, h = blockIdx.y, it = blockIdx.z;
  const int nv = nvp[b];
  const int i0 = it * 64;
  const int tid = threadIdx.x;
  const int w = tid >> 6, l = tid & 63;
  const int lo = l & 15, quad = l >> 4;

  __shared__ ushort Ks[2][64 * 64];  // 2 x 8 KB

  const int i = i0 + w * 16 + lo;
  const ushort* qp = q + (size_t)(b * T + i) * 512 + h * 64 + quad * 8;
  const short8 a0 = *(const short8*)qp;
  const short8 a1 = *(const short8*)(qp + 32);

  float lsum = 0.f;
  const int ntile = ((nv + 63) >> 6) - it;

  if (ntile > 0) {
    auto stage = [&](int buf, int jt) {
#pragma unroll
      for (int u = 0; u < 2; ++u) {
        const int s = u * 256 + tid;
        const int row = s >> 3, c = s & 7;
        gl_lds16(kv + (size_t)(b * T + jt * 64 + row) * 512 + h * 64 + ((c ^ (row & 7)) * 8),
                 Ks[buf] + (size_t)(u * 256 + w * 64) * 8);
      }
    };
    stage(0, it);
    __syncthreads();
    for (int s = 0; s < ntile; ++s) {
      if (s + 1 < ntile) stage((s + 1) & 1, it + s + 1);
      const ushort* kbase = Ks[s & 1];
      const int j0 = (it + s) * 64;
      const bool diag = (s == 0);
      const bool masked = diag | (j0 + 64 > nv);
#pragma unroll
      for (int ni = 0; ni < 4; ++ni) {
        if (diag && ni < w) continue;  // sub-tile fully below diagonal (wave-uniform)
        const int rw = ni * 16 + lo;
        const short8 b0 = *(const short8*)(kbase + (size_t)rw * 64 + ((quad ^ (rw & 7)) * 8));
        const short8 b1 = *(const short8*)(kbase + (size_t)rw * 64 + (((4 + quad) ^ (rw & 7)) * 8));
        f32x4 acc = (f32x4){0.f, 0.f, 0.f, 0.f};
        acc = __builtin_amdgcn_mfma_f32_16x16x32_bf16(b0, a0, acc, 0, 0, 0);
        acc = __builtin_amdgcn_mfma_f32_16x16x32_bf16(b1, a1, acc, 0, 0, 0);
        if (!masked) {
#pragma unroll
          for (int r = 0; r < 4; ++r) lsum += __builtin_amdgcn_exp2f(acc[r] * SC);
        } else {
          const int jb = j0 + ni * 16 + quad * 4;
#pragma unroll
          for (int r = 0; r < 4; ++r) {
            const int j = jb + r;
            if (j > i && j < nv) lsum += __builtin_amdgcn_exp2f(acc[r] * SC);
          }
        }
      }
      __syncthreads();
    }
  }

  lsum += __shfl_xor(lsum, 16, 64);
  lsum += __shfl_xor(lsum, 32, 64);
  if (quad == 0) {
    const size_t row = (size_t)(b * T) + i;
    Wt[(size_t)h * NROW + row] =
        (lsum > 0.f) ? (g[row * 8 + h] - __logf(lsum)) : NEG_INF;
  }
}

// ---------------------------------------------------------------- pass2 (unchanged)
__global__ __launch_bounds__(512) void k_pass2(
    const ushort* __restrict__ q, const ushort* __restrict__ kv,
    const float* __restrict__ Wt, const int* __restrict__ nvp,
    float* __restrict__ out) {
  const int b = blockIdx.x, jt = blockIdx.y, it = blockIdx.z;
  const int nv = nvp[b];
  const int i0 = it * 128, j0 = jt * 128;
  const int tid = threadIdx.x;

  if (jt < it || j0 >= nv) {
    const int r0 = tid >> 5, c0 = (tid & 31) * 4;
    float4 v; v.x = v.y = v.z = v.w = SENT;
#pragma unroll
    for (int u = 0; u < 8; ++u)
      *(float4*)(out + ((size_t)(b * T + i0 + r0 + u * 16)) * T + j0 + c0) = v;
    return;
  }

  const int w = tid >> 6, l = tid & 63;
  const int lo = l & 15, quad = l >> 4;
  const int qi = w & 3, qj = w >> 2;  // wave tile: i = qi*32..+32, j = qj*64..+64

  __shared__ ushort Qs[2][128 * 64];  // 2 x 16 KB
  __shared__ ushort Ks[2][128 * 64];  // 2 x 16 KB

  auto stage = [&](int buf, int h) {
#pragma unroll
    for (int u = 0; u < 2; ++u) {
      const int s = u * 512 + tid;        // 0..1023 chunk id
      const int row = s >> 3, c = s & 7;  // row 0..127, chunk 0..7
      gl_lds16(q  + (size_t)(b * T + i0 + row) * 512 + h * 64 + ((c ^ (row & 7)) * 8),
               Qs[buf] + (size_t)(u * 512 + w * 64) * 8);
      gl_lds16(kv + (size_t)(b * T + j0 + row) * 512 + h * 64 + ((c ^ (row & 7)) * 8),
               Ks[buf] + (size_t)(u * 512 + w * 64) * 8);
    }
  };

  stage(0, 0);  // head 0 in flight

  // per-row gate/denominator weights for this wave's 2 i-frags (16 scalars)
  float wl[2][8];
#pragma unroll
  for (int mi = 0; mi < 2; ++mi) {
    const int i = i0 + qi * 32 + mi * 16 + lo;
#pragma unroll
    for (int h = 0; h < 8; ++h)
      wl[mi][h] = Wt[(size_t)h * NROW + b * T + i] * LOG2E;  // -inf stays -inf
  }

  float se[2][4][4];  // [mi][ni][r]
#pragma unroll
  for (int a = 0; a < 2; ++a)
#pragma unroll
    for (int c = 0; c < 4; ++c)
#pragma unroll
      for (int r = 0; r < 4; ++r) se[a][c][r] = 0.f;

  __syncthreads();  // head-0 staging complete

#pragma unroll
  for (int h = 0; h < 8; ++h) {
    if (h < 7) stage((h + 1) & 1, h + 1);  // prefetch next head under this compute
    const ushort* Qb = Qs[h & 1];
    const ushort* Kb = Ks[h & 1];
    f32x4 acc[2][4];
#pragma unroll
    for (int mi = 0; mi < 2; ++mi)
#pragma unroll
      for (int ni = 0; ni < 4; ++ni) acc[mi][ni] = (f32x4){0.f, 0.f, 0.f, 0.f};
#pragma unroll
    for (int kk = 0; kk < 2; ++kk) {
      const int swz = ((kk * 4 + quad) ^ (lo & 7)) * 8;  // row&7 == lo&7 (offsets %8==0)
      short8 qf[2], kf[4];
#pragma unroll
      for (int mi = 0; mi < 2; ++mi)
        qf[mi] = *(const short8*)(Qb + (size_t)(qi * 32 + mi * 16 + lo) * 64 + swz);
#pragma unroll
      for (int ni = 0; ni < 4; ++ni)
        kf[ni] = *(const short8*)(Kb + (size_t)(qj * 64 + ni * 16 + lo) * 64 + swz);
#pragma unroll
      for (int mi = 0; mi < 2; ++mi)
#pragma unroll
        for (int ni = 0; ni < 4; ++ni)
          acc[mi][ni] = __builtin_amdgcn_mfma_f32_16x16x32_bf16(kf[ni], qf[mi], acc[mi][ni], 0, 0, 0);
    }
#pragma unroll
    for (int mi = 0; mi < 2; ++mi)
#pragma unroll
      for (int ni = 0; ni < 4; ++ni)
#pragma unroll
        for (int r = 0; r < 4; ++r)
          se[mi][ni][r] += __builtin_amdgcn_exp2f(acc[mi][ni][r] * SC + wl[mi][h]);
    if (h < 7) __syncthreads();  // next-head staging drained + buffer reuse safe
  }

  // epilogue: lane owns row i; per (ni) 4 consecutive j -> float4 stores
#pragma unroll
  for (int mi = 0; mi < 2; ++mi) {
    const int i = i0 + qi * 32 + mi * 16 + lo;
    const size_t orow = ((size_t)(b * T + i)) * T;
#pragma unroll
    for (int ni = 0; ni < 4; ++ni) {
      const int jb = j0 + qj * 64 + ni * 16 + quad * 4;
      float4 v;
      v.x = (jb + 0 > i && jb + 0 < nv) ? fmaxf(__logf(se[mi][ni][0]), SENT) : SENT;
      v.y = (jb + 1 > i && jb + 1 < nv) ? fmaxf(__logf(se[mi][ni][1]), SENT) : SENT;
      v.z = (jb + 2 > i && jb + 2 < nv) ? fmaxf(__logf(se[mi][ni][2]), SENT) : SENT;
      v.w = (jb + 3 > i && jb + 3 < nv) ? fmaxf(__logf(se[mi][ni][3]), SENT) : SENT;
      *(float4*)(out + orow + jb) = v;
    }
  }
}

// ---------------------------------------------------------------- launch
extern "C" void kernel_launch(void* const* d_in, const int* in_sizes, int n_in,
                              void* d_out, int out_size, void* d_ws, size_t ws_size,
                              hipStream_t stream) {
  (void)in_sizes; (void)n_in; (void)out_size; (void)ws_size;
  const float* feat = (const float*)d_in[0];
  const float* pos  = (const float*)d_in[1];
  const int* tokens = (const int*)d_in[2];
  const float* Wq = (const float*)d_in[3];
  const float* bq = (const float*)d_in[4];
  const float* Wk = (const float*)d_in[5];
  const float* bk = (const float*)d_in[6];
  const float* Wg = (const float*)d_in[7];
  const float* bg = (const float*)d_in[8];
  float* out = (float*)d_out;

  // workspace: qbuf 8.4M | kbuf 8.4M | Wbf 2M | gbuf 256K | Wt 256K | nv
  ushort* qbuf = (ushort*)d_ws;
  ushort* kbuf = qbuf + (size_t)NROW * 512;
  ushort* Wbf  = kbuf + (size_t)NROW * 512;
  float*  gbuf = (float*)(Wbf + (size_t)1024 * 1024);
  float*  Wt   = gbuf + (size_t)NROW * NH;
  int*    nv   = (int*)(Wt + (size_t)NH * NROW);

  // fbf (bf16 concat of feat,pos) lives in d_out; consumed by k_gemm,
  // fully overwritten later by k_pass2.
  ushort* fbf = (ushort*)d_out;

  k_prep<<<dim3(1544), dim3(256), 0, stream>>>(feat, pos, tokens, Wq, Wk, Wg, bg,
                                               fbf, Wbf, gbuf, nv);
  k_gemm<<<dim3(8, 64), dim3(256), 0, stream>>>(fbf, Wbf, bq, bk, qbuf, kbuf);
  k_pass1<<<dim3(BATCH, NH, 16), dim3(256), 0, stream>>>(qbuf, kbuf, gbuf, nv, Wt);
  k_pass2<<<dim3(BATCH, 8, 8), dim3(512), 0, stream>>>(qbuf, kbuf, Wt, nv, out);
}

// Round 8
// 157.363 us; speedup vs baseline: 1.2354x; 1.0174x over previous
//
#include <hip/hip_runtime.h>
#include <math.h>

#define BATCH 8
#define T 1024
#define NH 8
#define NROW 8192
#define NEG_INF (-INFINITY)
#define SENT (-1.0e30f)
#define SC 0.180336880f      // 0.125 * log2(e)
#define LOG2E 1.442695041f

typedef __attribute__((ext_vector_type(8))) short short8;    // 8 bf16 (4 VGPRs)
typedef __attribute__((ext_vector_type(4))) float f32x4;

// fp32 -> bf16 (RNE)
__device__ __forceinline__ ushort f2bf(float x) {
  uint u = __float_as_uint(x);
  return (ushort)((u + 0x7FFFu + ((u >> 16) & 1u)) >> 16);
}
__device__ __forceinline__ uint pack2(float a, float b) {
  return (uint)f2bf(a) | ((uint)f2bf(b) << 16);
}
// async global->LDS, 16B per lane; LDS dest = wave-uniform base + lane*16
__device__ __forceinline__ void gl_lds16(const ushort* g, ushort* l) {
  __builtin_amdgcn_global_load_lds(
      (const __attribute__((address_space(1))) unsigned int*)g,
      (__attribute__((address_space(3))) unsigned int*)l, 16, 0, 0);
}

// ---------------------------------------------------------------- merged prep
// blocks [0,1024): prep_fg (bf16 pack + gate log-softmax)
// blocks [1024,1536): prep_w (Wq/Wk -> bf16 concat)
// blocks [1536,1544): n_valid
__global__ __launch_bounds__(256) void k_prep(
    const float* __restrict__ feat, const float* __restrict__ pos,
    const int* __restrict__ tokens,
    const float* __restrict__ Wq, const float* __restrict__ Wk,
    const float* __restrict__ Wg, const float* __restrict__ bg,
    ushort* __restrict__ fbf, ushort* __restrict__ Wbf,
    float* __restrict__ gout, int* __restrict__ nvout) {
  const int bid = blockIdx.x;
  const int tid = threadIdx.x;

  if (bid < 1024) {
    // ---- prep_fg
    __shared__ __align__(16) float Ws[8192];  // 8 x 1024 fp32 = 32 KB
#pragma unroll
    for (int u = 0; u < 8; ++u)
      ((float4*)Ws)[u * 256 + tid] = ((const float4*)Wg)[u * 256 + tid];
    __syncthreads();

    const int w = tid >> 6, l = tid & 63;
    const int c0 = l * 16;
    const int row0 = bid * 8 + w * 2;

    float4 f[2][4];
#pragma unroll
    for (int r = 0; r < 2; ++r) {
      const int row = row0 + r;
      const float* src = (c0 < 512) ? (feat + (size_t)row * 512 + c0)
                                    : (pos + (size_t)row * 512 + (c0 - 512));
#pragma unroll
      for (int q4 = 0; q4 < 4; ++q4) f[r][q4] = *(const float4*)(src + q4 * 4);
      uint4 o0, o1;
      o0.x = pack2(f[r][0].x, f[r][0].y); o0.y = pack2(f[r][0].z, f[r][0].w);
      o0.z = pack2(f[r][1].x, f[r][1].y); o0.w = pack2(f[r][1].z, f[r][1].w);
      o1.x = pack2(f[r][2].x, f[r][2].y); o1.y = pack2(f[r][2].z, f[r][2].w);
      o1.z = pack2(f[r][3].x, f[r][3].y); o1.w = pack2(f[r][3].z, f[r][3].w);
      *(uint4*)(fbf + (size_t)row * 1024 + c0) = o0;
      *(uint4*)(fbf + (size_t)row * 1024 + c0 + 8) = o1;
    }

    float s[2][8];
#pragma unroll
    for (int h = 0; h < 8; ++h) {
      const float* wg = Ws + h * 1024 + c0;
      float4 w0 = *(const float4*)(wg + 0);
      float4 w1 = *(const float4*)(wg + 4);
      float4 w2 = *(const float4*)(wg + 8);
      float4 w3 = *(const float4*)(wg + 12);
#pragma unroll
      for (int r = 0; r < 2; ++r)
        s[r][h] = f[r][0].x * w0.x + f[r][0].y * w0.y + f[r][0].z * w0.z + f[r][0].w * w0.w
                + f[r][1].x * w1.x + f[r][1].y * w1.y + f[r][1].z * w1.z + f[r][1].w * w1.w
                + f[r][2].x * w2.x + f[r][2].y * w2.y + f[r][2].z * w2.z + f[r][2].w * w2.w
                + f[r][3].x * w3.x + f[r][3].y * w3.y + f[r][3].z * w3.z + f[r][3].w * w3.w;
    }
#pragma unroll
    for (int m = 1; m < 64; m <<= 1)
#pragma unroll
      for (int r = 0; r < 2; ++r)
#pragma unroll
        for (int h = 0; h < 8; ++h) s[r][h] += __shfl_xor(s[r][h], m, 64);
    if (l == 0) {
#pragma unroll
      for (int r = 0; r < 2; ++r) {
        float lg[8], mx = -1e30f;
#pragma unroll
        for (int h = 0; h < 8; ++h) { lg[h] = s[r][h] + bg[h]; mx = fmaxf(mx, lg[h]); }
        float sum = 0.f;
#pragma unroll
        for (int h = 0; h < 8; ++h) sum += __expf(lg[h] - mx);
        const float lse = mx + __logf(sum);
#pragma unroll
        for (int h = 0; h < 8; ++h) gout[(size_t)(row0 + r) * 8 + h] = lg[h] - lse;
      }
    }
  } else if (bid < 1536) {
    // ---- prep_w
    const int gid = (bid - 1024) * 256 + tid;  // 0..131071
    const int e0 = gid * 8;
    const int n = e0 >> 10, k = e0 & 1023;
    const float* src = (n < 512) ? (Wq + (size_t)n * 1024 + k)
                                 : (Wk + (size_t)(n - 512) * 1024 + k);
    float4 a = *(const float4*)src;
    float4 b = *(const float4*)(src + 4);
    uint4 o;
    o.x = pack2(a.x, a.y); o.y = pack2(a.z, a.w);
    o.z = pack2(b.x, b.y); o.w = pack2(b.z, b.w);
    *(uint4*)(Wbf + (size_t)n * 1024 + k) = o;
  } else {
    // ---- n_valid
    const int b = bid - 1536;
    int cnt = 0;
    for (int i = tid; i < T; i += 256) cnt += (tokens[b * T + i] != 0) ? 1 : 0;
    __shared__ int s[256];
    s[tid] = cnt;
    __syncthreads();
    for (int st = 128; st > 0; st >>= 1) {
      if (tid < st) s[tid] += s[tid + st];
      __syncthreads();
    }
    if (tid == 0) nvout[b] = s[0];
  }
}

// ---------------------------------------------------------------- fused q/k GEMM
// 128x128 tile, BK=64, 2-phase prefetch dbuf, T2 XOR-chunk swizzle (r7, verified),
// XCD-chunked block swizzle. NEW (r8): 512 threads / 8 waves per block (wave owns
// 64x32) — same 64 KB LDS keeps 2 blocks/CU, but waves/SIMD double 2 -> 4 so the
// other block's waves cover this block's stage-drain stall (m114 mechanism).
__global__ __launch_bounds__(512, 4) void k_gemm(
    const ushort* __restrict__ fbf, const ushort* __restrict__ Wbf,
    const float* __restrict__ bq, const float* __restrict__ bk,
    ushort* __restrict__ qbuf, ushort* __restrict__ kbuf) {
  const int g = blockIdx.x + 8 * blockIdx.y;   // dispatch-linear id; xcd ~ g%8
  const int wid = (g & 7) * 64 + (g >> 3);     // bijective (512 = 8*64)
  const int n0 = (wid & 7) * 128;
  const int m0 = (wid >> 3) * 128;
  const int tid = threadIdx.x;
  const int w = tid >> 6, l = tid & 63;
  const int lo = l & 15, quad = l >> 4;
  const int wm0 = (w >> 2) * 64;   // wave m-offset: 0 or 64
  const int wn0 = (w & 3) * 32;    // wave n-offset: 0,32,64,96

  __shared__ ushort As[2][128 * 64];  // 2 x 16 KB, linear row-major [128][64]
  __shared__ ushort Bs[2][128 * 64];

  f32x4 acc[4][2];
#pragma unroll
  for (int i = 0; i < 4; ++i)
#pragma unroll
    for (int j = 0; j < 2; ++j) acc[i][j] = (f32x4){0.f, 0.f, 0.f, 0.f};

  // lane's dest LDS row&7 == (tid>>3)&7; pre-swizzled source chunk:
  const int csw = ((tid & 7) ^ ((tid >> 3) & 7)) * 8;
  const int r0 = tid >> 3;  // 0..63; dest rows u*64 + r0

  auto stage = [&](int buf, int k0) {
#pragma unroll
    for (int u = 0; u < 2; ++u) {
      gl_lds16(fbf + (size_t)(m0 + u * 64 + r0) * 1024 + k0 + csw,
               As[buf] + (size_t)(u * 512 + w * 64) * 8);
      gl_lds16(Wbf + (size_t)(n0 + u * 64 + r0) * 1024 + k0 + csw,
               Bs[buf] + (size_t)(u * 512 + w * 64) * 8);
    }
  };

  stage(0, 0);
  int cur = 0;
  for (int k0 = 0; k0 < 1024; k0 += 64) {
    __syncthreads();  // drains vmcnt: buf[cur] staged; buf[cur^1] readers done
    if (k0 + 64 < 1024) stage(cur ^ 1, k0 + 64);  // in flight during compute
    const ushort* pA = As[cur];
    const ushort* pB = Bs[cur];
#pragma unroll
    for (int kk = 0; kk < 2; ++kk) {
      const int swz = ((kk * 4 + quad) ^ (lo & 7)) * 8;  // frag row&7 == lo&7
      short8 af[4], bfr[2];
#pragma unroll
      for (int mi = 0; mi < 4; ++mi)
        af[mi] = *(const short8*)(pA + (size_t)(wm0 + mi * 16 + lo) * 64 + swz);
#pragma unroll
      for (int ni = 0; ni < 2; ++ni)
        bfr[ni] = *(const short8*)(pB + (size_t)(wn0 + ni * 16 + lo) * 64 + swz);
#pragma unroll
      for (int mi = 0; mi < 4; ++mi)
#pragma unroll
        for (int ni = 0; ni < 2; ++ni)  // swapped: rows=n, cols=m
          acc[mi][ni] = __builtin_amdgcn_mfma_f32_16x16x32_bf16(bfr[ni], af[mi], acc[mi][ni], 0, 0, 0);
    }
    cur ^= 1;
  }

  // epilogue: lane owns row m, 4 consecutive n per (ni)
  float4 bias4[2];
#pragma unroll
  for (int ni = 0; ni < 2; ++ni) {
    const int gn = n0 + wn0 + ni * 16 + quad * 4;
    bias4[ni] = *(const float4*)((gn < 512) ? (bq + gn) : (bk + gn - 512));
  }
#pragma unroll
  for (int mi = 0; mi < 4; ++mi) {
    const int m = m0 + wm0 + mi * 16 + lo;
#pragma unroll
    for (int ni = 0; ni < 2; ++ni) {
      const int gn = n0 + wn0 + ni * 16 + quad * 4;
      ushort* dst = (gn < 512) ? (qbuf + (size_t)m * 512 + gn)
                               : (kbuf + (size_t)m * 512 + gn - 512);
      ushort4 o;
      o.x = f2bf(acc[mi][ni][0] + bias4[ni].x);
      o.y = f2bf(acc[mi][ni][1] + bias4[ni].y);
      o.z = f2bf(acc[mi][ni][2] + bias4[ni].z);
      o.w = f2bf(acc[mi][ni][3] + bias4[ni].w);
      *(ushort4*)dst = o;
    }
  }
}

// ---------------------------------------------------------------- pass1 (unchanged)
__global__ __launch_bounds__(256) void k_pass1(
    const ushort* __restrict__ q, const ushort* __restrict__ kv,
    const float* __restrict__ g, const int* __restrict__ nvp,
    float* __restrict__ Wt) {
  const int b = blockIdx.x, h = blockIdx.y, it = blockIdx.z;
  const int nv = nvp[b];
  const int i0 = it * 64;
  const int tid = threadIdx.x;
  const int w = tid >> 6, l = tid & 63;
  const int lo = l & 15, quad = l >> 4;

  __shared__ ushort Ks[2][64 * 64];  // 2 x 8 KB

  const int i = i0 + w * 16 + lo;
  const ushort* qp = q + (size_t)(b * T + i) * 512 + h * 64 + quad * 8;
  const short8 a0 = *(const short8*)qp;
  const short8 a1 = *(const short8*)(qp + 32);

  float lsum = 0.f;
  const int ntile = ((nv + 63) >> 6) - it;

  if (ntile > 0) {
    auto stage = [&](int buf, int jt) {
#pragma unroll
      for (int u = 0; u < 2; ++u) {
        const int s = u * 256 + tid;
        const int row = s >> 3, c = s & 7;
        gl_lds16(kv + (size_t)(b * T + jt * 64 + row) * 512 + h * 64 + ((c ^ (row & 7)) * 8),
                 Ks[buf] + (size_t)(u * 256 + w * 64) * 8);
      }
    };
    stage(0, it);
    __syncthreads();
    for (int s = 0; s < ntile; ++s) {
      if (s + 1 < ntile) stage((s + 1) & 1, it + s + 1);
      const ushort* kbase = Ks[s & 1];
      const int j0 = (it + s) * 64;
      const bool diag = (s == 0);
      const bool masked = diag | (j0 + 64 > nv);
#pragma unroll
      for (int ni = 0; ni < 4; ++ni) {
        if (diag && ni < w) continue;  // sub-tile fully below diagonal (wave-uniform)
        const int rw = ni * 16 + lo;
        const short8 b0 = *(const short8*)(kbase + (size_t)rw * 64 + ((quad ^ (rw & 7)) * 8));
        const short8 b1 = *(const short8*)(kbase + (size_t)rw * 64 + (((4 + quad) ^ (rw & 7)) * 8));
        f32x4 acc = (f32x4){0.f, 0.f, 0.f, 0.f};
        acc = __builtin_amdgcn_mfma_f32_16x16x32_bf16(b0, a0, acc, 0, 0, 0);
        acc = __builtin_amdgcn_mfma_f32_16x16x32_bf16(b1, a1, acc, 0, 0, 0);
        if (!masked) {
#pragma unroll
          for (int r = 0; r < 4; ++r) lsum += __builtin_amdgcn_exp2f(acc[r] * SC);
        } else {
          const int jb = j0 + ni * 16 + quad * 4;
#pragma unroll
          for (int r = 0; r < 4; ++r) {
            const int j = jb + r;
            if (j > i && j < nv) lsum += __builtin_amdgcn_exp2f(acc[r] * SC);
          }
        }
      }
      __syncthreads();
    }
  }

  lsum += __shfl_xor(lsum, 16, 64);
  lsum += __shfl_xor(lsum, 32, 64);
  if (quad == 0) {
    const size_t row = (size_t)(b * T) + i;
    Wt[(size_t)h * NROW + row] =
        (lsum > 0.f) ? (g[row * 8 + h] - __logf(lsum)) : NEG_INF;
  }
}

// ---------------------------------------------------------------- pass2 (unchanged)
__global__ __launch_bounds__(512) void k_pass2(
    const ushort* __restrict__ q, const ushort* __restrict__ kv,
    const float* __restrict__ Wt, const int* __restrict__ nvp,
    float* __restrict__ out) {
  const int b = blockIdx.x, jt = blockIdx.y, it = blockIdx.z;
  const int nv = nvp[b];
  const int i0 = it * 128, j0 = jt * 128;
  const int tid = threadIdx.x;

  if (jt < it || j0 >= nv) {
    const int r0 = tid >> 5, c0 = (tid & 31) * 4;
    float4 v; v.x = v.y = v.z = v.w = SENT;
#pragma unroll
    for (int u = 0; u < 8; ++u)
      *(float4*)(out + ((size_t)(b * T + i0 + r0 + u * 16)) * T + j0 + c0) = v;
    return;
  }

  const int w = tid >> 6, l = tid & 63;
  const int lo = l & 15, quad = l >> 4;
  const int qi = w & 3, qj = w >> 2;  // wave tile: i = qi*32..+32, j = qj*64..+64

  __shared__ ushort Qs[2][128 * 64];  // 2 x 16 KB
  __shared__ ushort Ks[2][128 * 64];  // 2 x 16 KB

  auto stage = [&](int buf, int h) {
#pragma unroll
    for (int u = 0; u < 2; ++u) {
      const int s = u * 512 + tid;        // 0..1023 chunk id
      const int row = s >> 3, c = s & 7;  // row 0..127, chunk 0..7
      gl_lds16(q  + (size_t)(b * T + i0 + row) * 512 + h * 64 + ((c ^ (row & 7)) * 8),
               Qs[buf] + (size_t)(u * 512 + w * 64) * 8);
      gl_lds16(kv + (size_t)(b * T + j0 + row) * 512 + h * 64 + ((c ^ (row & 7)) * 8),
               Ks[buf] + (size_t)(u * 512 + w * 64) * 8);
    }
  };

  stage(0, 0);  // head 0 in flight

  // per-row gate/denominator weights for this wave's 2 i-frags (16 scalars)
  float wl[2][8];
#pragma unroll
  for (int mi = 0; mi < 2; ++mi) {
    const int i = i0 + qi * 32 + mi * 16 + lo;
#pragma unroll
    for (int h = 0; h < 8; ++h)
      wl[mi][h] = Wt[(size_t)h * NROW + b * T + i] * LOG2E;  // -inf stays -inf
  }

  float se[2][4][4];  // [mi][ni][r]
#pragma unroll
  for (int a = 0; a < 2; ++a)
#pragma unroll
    for (int c = 0; c < 4; ++c)
#pragma unroll
      for (int r = 0; r < 4; ++r) se[a][c][r] = 0.f;

  __syncthreads();  // head-0 staging complete

#pragma unroll
  for (int h = 0; h < 8; ++h) {
    if (h < 7) stage((h + 1) & 1, h + 1);  // prefetch next head under this compute
    const ushort* Qb = Qs[h & 1];
    const ushort* Kb = Ks[h & 1];
    f32x4 acc[2][4];
#pragma unroll
    for (int mi = 0; mi < 2; ++mi)
#pragma unroll
      for (int ni = 0; ni < 4; ++ni) acc[mi][ni] = (f32x4){0.f, 0.f, 0.f, 0.f};
#pragma unroll
    for (int kk = 0; kk < 2; ++kk) {
      const int swz = ((kk * 4 + quad) ^ (lo & 7)) * 8;  // row&7 == lo&7 (offsets %8==0)
      short8 qf[2], kf[4];
#pragma unroll
      for (int mi = 0; mi < 2; ++mi)
        qf[mi] = *(const short8*)(Qb + (size_t)(qi * 32 + mi * 16 + lo) * 64 + swz);
#pragma unroll
      for (int ni = 0; ni < 4; ++ni)
        kf[ni] = *(const short8*)(Kb + (size_t)(qj * 64 + ni * 16 + lo) * 64 + swz);
#pragma unroll
      for (int mi = 0; mi < 2; ++mi)
#pragma unroll
        for (int ni = 0; ni < 4; ++ni)
          acc[mi][ni] = __builtin_amdgcn_mfma_f32_16x16x32_bf16(kf[ni], qf[mi], acc[mi][ni], 0, 0, 0);
    }
#pragma unroll
    for (int mi = 0; mi < 2; ++mi)
#pragma unroll
      for (int ni = 0; ni < 4; ++ni)
#pragma unroll
        for (int r = 0; r < 4; ++r)
          se[mi][ni][r] += __builtin_amdgcn_exp2f(acc[mi][ni][r] * SC + wl[mi][h]);
    if (h < 7) __syncthreads();  // next-head staging drained + buffer reuse safe
  }

  // epilogue: lane owns row i; per (ni) 4 consecutive j -> float4 stores
#pragma unroll
  for (int mi = 0; mi < 2; ++mi) {
    const int i = i0 + qi * 32 + mi * 16 + lo;
    const size_t orow = ((size_t)(b * T + i)) * T;
#pragma unroll
    for (int ni = 0; ni < 4; ++ni) {
      const int jb = j0 + qj * 64 + ni * 16 + quad * 4;
      float4 v;
      v.x = (jb + 0 > i && jb + 0 < nv) ? fmaxf(__logf(se[mi][ni][0]), SENT) : SENT;
      v.y = (jb + 1 > i && jb + 1 < nv) ? fmaxf(__logf(se[mi][ni][1]), SENT) : SENT;
      v.z = (jb + 2 > i && jb + 2 < nv) ? fmaxf(__logf(se[mi][ni][2]), SENT) : SENT;
      v.w = (jb + 3 > i && jb + 3 < nv) ? fmaxf(__logf(se[mi][ni][3]), SENT) : SENT;
      *(float4*)(out + orow + jb) = v;
    }
  }
}

// ---------------------------------------------------------------- launch
extern "C" void kernel_launch(void* const* d_in, const int* in_sizes, int n_in,
                              void* d_out, int out_size, void* d_ws, size_t ws_size,
                              hipStream_t stream) {
  (void)in_sizes; (void)n_in; (void)out_size; (void)ws_size;
  const float* feat = (const float*)d_in[0];
  const float* pos  = (const float*)d_in[1];
  const int* tokens = (const int*)d_in[2];
  const float* Wq = (const float*)d_in[3];
  const float* bq = (const float*)d_in[4];
  const float* Wk = (const float*)d_in[5];
  const float* bk = (const float*)d_in[6];
  const float* Wg = (const float*)d_in[7];
  const float* bg = (const float*)d_in[8];
  float* out = (float*)d_out;

  // workspace: qbuf 8.4M | kbuf 8.4M | Wbf 2M | gbuf 256K | Wt 256K | nv
  ushort* qbuf = (ushort*)d_ws;
  ushort* kbuf = qbuf + (size_t)NROW * 512;
  ushort* Wbf  = kbuf + (size_t)NROW * 512;
  float*  gbuf = (float*)(Wbf + (size_t)1024 * 1024);
  float*  Wt   = gbuf + (size_t)NROW * NH;
  int*    nv   = (int*)(Wt + (size_t)NH * NROW);

  // fbf (bf16 concat of feat,pos) lives in d_out; consumed by k_gemm,
  // fully overwritten later by k_pass2.
  ushort* fbf = (ushort*)d_out;

  k_prep<<<dim3(1544), dim3(256), 0, stream>>>(feat, pos, tokens, Wq, Wk, Wg, bg,
                                               fbf, Wbf, gbuf, nv);
  k_gemm<<<dim3(8, 64), dim3(512), 0, stream>>>(fbf, Wbf, bq, bk, qbuf, kbuf);
  k_pass1<<<dim3(BATCH, NH, 16), dim3(256), 0, stream>>>(qbuf, kbuf, gbuf, nv, Wt);
  k_pass2<<<dim3(BATCH, 8, 8), dim3(512), 0, stream>>>(qbuf, kbuf, Wt, nv, out);
}